// Round 1
// baseline (2177.101 us; speedup 1.0000x reference)
//
#include <hip/hip_runtime.h>

// RealizedGARCH-PINN scan. B=4096 chains, T=2048 sequential steps each.
// One wave (64 lanes) per chain; lane j owns column j of every layer.
// FP32 baseline: L2 (64x64 matvec) = 64 fp32 FMA/lane/step; h1 broadcast
// through a wave-local double-buffered LDS slot; L3 via shfl_xor butterfly.

constexpr int Bn  = 4096;
constexpr int Tn  = 2048;
constexpr int WPB = 4;   // waves per block (256 threads)

__global__ __launch_bounds__(256, 4)
void garch_scan_kernel(const float* __restrict__ g_ret,
                       const float* __restrict__ g_lrv,
                       const float* __restrict__ p_omega,
                       const float* __restrict__ p_beta,
                       const float* __restrict__ p_tau1,
                       const float* __restrict__ p_tau2,
                       const float* __restrict__ p_gamma,
                       const float* __restrict__ p_xi,
                       const float* __restrict__ p_phi,
                       const float* __restrict__ p_delta1,
                       const float* __restrict__ p_delta2,
                       const float* __restrict__ p_mu,
                       const float* __restrict__ W1,
                       const float* __restrict__ b1,
                       const float* __restrict__ W2,
                       const float* __restrict__ b2,
                       const float* __restrict__ W3,
                       const float* __restrict__ b3,
                       float* __restrict__ out)
{
    const int lane = threadIdx.x & 63;
    const int wv   = threadIdx.x >> 6;
    const int b    = blockIdx.x * WPB + wv;

    // wave-uniform GARCH scalars (compiler lifts to SGPRs)
    const float omega = p_omega[0], beta = p_beta[0];
    const float tau1 = p_tau1[0], tau2 = p_tau2[0], gam = p_gamma[0];
    const float xi = p_xi[0], phi = p_phi[0];
    const float d1 = p_delta1[0], d2 = p_delta2[0], mu = p_mu[0];
    const float b3s = b3[0];

    // lane j holds column j of W1/b1/b2/W3 and the full column j of W2 (64 VGPRs)
    const float w10 = W1[lane], w11 = W1[64 + lane], w12 = W1[128 + lane];
    const float b1j = b1[lane], b2j = b2[lane], w3j = W3[lane];

    float w2c[64];
#pragma unroll
    for (int k = 0; k < 64; ++k) w2c[k] = W2[k * 64 + lane];

    __shared__ float4 h1buf[WPB][2][16];   // double-buffered h1 per wave
    __shared__ float2 rlbuf[WPB][64];      // (return, log_rv) chunk per wave

    const float* rptr = g_ret + (long)b * Tn;
    const float* lptr = g_lrv + (long)b * Tn;
    float* oLH = out + 0l * Bn * Tn + (long)b * Tn;
    float* oLX = out + 1l * Bn * Tn + (long)b * Tn;
    float* oZ  = out + 2l * Bn * Tn + (long)b * Tn;
    float* oU  = out + 3l * Bn * Tn + (long)b * Tn;

    float lh = 0.0f, zp = 0.0f, up = 0.0f;   // carried (enh, z, u)

    for (int t0 = 0; t0 < Tn; t0 += 64) {
        // stage 64 timesteps of inputs (coalesced 64x8B)
        rlbuf[wv][lane] = make_float2(rptr[t0 + lane], lptr[t0 + lane]);
        asm volatile("s_waitcnt lgkmcnt(0)" ::: "memory");

        float o_lh = 0.0f, o_lx = 0.0f, o_z = 0.0f, o_u = 0.0f;

        for (int tm = 0; tm < 64; ++tm) {
            const float2 rl = rlbuf[wv][tm];           // uniform-addr broadcast read
            const float r_t = rl.x, lrv_t = rl.y;

            float lh_t;
            if (t0 == 0 && tm == 0) {
                // log(mean(exp(lrv[:,0:1]))) == lrv[:,0]
                lh_t = lrv_t;
            } else {
                lh_t = omega + beta * lh + tau1 * zp
                     + tau2 * (zp * zp - 1.0f) + gam * up;
            }

            // measurement equation
            const float z_t   = (r_t - mu) * __expf(-0.5f * lh_t); // (r-mu)/sqrt(exp(lh))
            const float dlt   = fmaf(d2, fmaf(z_t, z_t, -1.0f), d1 * z_t);
            const float a_t   = xi + phi * lh_t + dlt;
            const float u_t   = lrv_t - a_t;
            const float lx_t  = a_t + u_t;                          // == lrv_t

            // layer 1: h1[j] = relu(x @ W1 + b1), x = [lh_t, z_t, u_t]
            const float h1 = fmaxf(fmaf(w12, u_t, fmaf(w11, z_t, fmaf(w10, lh_t, b1j))), 0.0f);

            // broadcast h1 through wave-local LDS (double-buffered)
            float* hw = (tm & 1) ? (float*)&h1buf[wv][1][0] : (float*)&h1buf[wv][0][0];
            hw[lane] = h1;
            asm volatile("s_waitcnt lgkmcnt(0)" ::: "memory");

            // layer 2: h2[j] = relu(sum_k h1[k]*W2[k][j] + b2[j])
            const float4* h4 = (const float4*)hw;
            float a0 = 0.0f, a1 = 0.0f, a2 = 0.0f, a3 = 0.0f;
#pragma unroll
            for (int kk = 0; kk < 16; ++kk) {
                const float4 v = h4[kk];                // broadcast (same addr, free)
                a0 = fmaf(v.x, w2c[4 * kk + 0], a0);
                a1 = fmaf(v.y, w2c[4 * kk + 1], a1);
                a2 = fmaf(v.z, w2c[4 * kk + 2], a2);
                a3 = fmaf(v.w, w2c[4 * kk + 3], a3);
            }
            const float h2 = fmaxf(((a0 + a1) + (a2 + a3)) + b2j, 0.0f);

            // layer 3: nn = sum_j h2[j]*W3[j] + b3  (butterfly -> all lanes)
            float p = h2 * w3j;
#pragma unroll
            for (int m = 1; m < 64; m <<= 1) p += __shfl_xor(p, m, 64);
            const float nn  = p + b3s;
            const float enh = fmaf(0.01f, nn, lh_t);

            lh = enh; zp = z_t; up = u_t;

            // lane tm keeps timestep t0+tm for the coalesced chunk store
            if (lane == tm) { o_lh = enh; o_lx = lx_t; o_z = z_t; o_u = u_t; }
        }

        oLH[t0 + lane] = o_lh;
        oLX[t0 + lane] = o_lx;
        oZ [t0 + lane] = o_z;
        oU [t0 + lane] = o_u;
    }
}

extern "C" void kernel_launch(void* const* d_in, const int* in_sizes, int n_in,
                              void* d_out, int out_size, void* d_ws, size_t ws_size,
                              hipStream_t stream) {
    const float* g_ret = (const float*)d_in[0];
    const float* g_lrv = (const float*)d_in[1];
    const float* p_omega  = (const float*)d_in[2];
    const float* p_beta   = (const float*)d_in[3];
    const float* p_tau1   = (const float*)d_in[4];
    const float* p_tau2   = (const float*)d_in[5];
    const float* p_gamma  = (const float*)d_in[6];
    const float* p_xi     = (const float*)d_in[7];
    const float* p_phi    = (const float*)d_in[8];
    const float* p_delta1 = (const float*)d_in[9];
    const float* p_delta2 = (const float*)d_in[10];
    const float* p_mu     = (const float*)d_in[11];
    const float* W1 = (const float*)d_in[12];
    const float* b1 = (const float*)d_in[13];
    const float* W2 = (const float*)d_in[14];
    const float* b2 = (const float*)d_in[15];
    const float* W3 = (const float*)d_in[16];
    const float* b3 = (const float*)d_in[17];
    float* out = (float*)d_out;

    dim3 grid(Bn / WPB), block(256);
    hipLaunchKernelGGL(garch_scan_kernel, grid, block, 0, stream,
                       g_ret, g_lrv, p_omega, p_beta, p_tau1, p_tau2, p_gamma,
                       p_xi, p_phi, p_delta1, p_delta2, p_mu,
                       W1, b1, W2, b2, W3, b3, out);
}

// Round 2
// 1392.035 us; speedup vs baseline: 1.5640x; 1.5640x over previous
//
#include <hip/hip_runtime.h>

// RealizedGARCH-PINN scan. B=4096 chains, T=2048 sequential steps.
// One wave per chain (4096 waves -> 4 waves/SIMD at 256thr/4wg blocks).
// Lane j owns column j of every layer. W2 held as 32 packed-f16 pairs
// per lane (32 VGPRs -- avoids the R1 spill of 64 fp32 regs).
// L2 matvec: 32x v_dot2_f32_f16 (2 MAC/inst, fp32 accum) against h1
// broadcast from LDS as f16 (uniform-address ds_read_b128 = free).

constexpr int Bn  = 4096;
constexpr int Tn  = 2048;
constexpr int WPB = 4;   // waves per block (256 threads)

typedef _Float16 h2v __attribute__((ext_vector_type(2)));

#if __has_builtin(__builtin_amdgcn_fdot2)
#define HAVE_FDOT2 1
#else
#define HAVE_FDOT2 0
#endif

__global__ __launch_bounds__(256, 4)
void garch_scan_kernel(const float* __restrict__ g_ret,
                       const float* __restrict__ g_lrv,
                       const float* __restrict__ p_omega,
                       const float* __restrict__ p_beta,
                       const float* __restrict__ p_tau1,
                       const float* __restrict__ p_tau2,
                       const float* __restrict__ p_gamma,
                       const float* __restrict__ p_xi,
                       const float* __restrict__ p_phi,
                       const float* __restrict__ p_delta1,
                       const float* __restrict__ p_delta2,
                       const float* __restrict__ p_mu,
                       const float* __restrict__ W1,
                       const float* __restrict__ b1,
                       const float* __restrict__ W2,
                       const float* __restrict__ b2,
                       const float* __restrict__ W3,
                       const float* __restrict__ b3,
                       float* __restrict__ out)
{
    const int lane = threadIdx.x & 63;
    const int wv   = threadIdx.x >> 6;
    const int b    = blockIdx.x * WPB + wv;

    // wave-uniform GARCH scalars (lifted to SGPRs)
    const float omega = p_omega[0], beta = p_beta[0];
    const float tau1 = p_tau1[0], tau2 = p_tau2[0], gam = p_gamma[0];
    const float xi = p_xi[0], phi = p_phi[0];
    const float d1 = p_delta1[0], d2 = p_delta2[0], mu = p_mu[0];
    const float b3s = b3[0];

    // lane j: column j of W1/b1/b2/W3 (fp32) and column j of W2 as 32 f16 pairs
    const float w10 = W1[lane], w11 = W1[64 + lane], w12 = W1[128 + lane];
    const float b1j = b1[lane], b2j = b2[lane], w3j = W3[lane];

    h2v w2p[32];
#pragma unroll
    for (int p = 0; p < 32; ++p) {
        const float a = W2[(2 * p) * 64 + lane];      // coalesced row reads
        const float c = W2[(2 * p + 1) * 64 + lane];
        h2v w; w.x = (_Float16)a; w.y = (_Float16)c;
        w2p[p] = w;
    }

    __shared__ __align__(16) _Float16 h1f[WPB][2][64];  // double-buffered h1 (f16)
    __shared__ float2 rlbuf[WPB][64];                   // staged (ret, log_rv) chunk

    const float* rptr = g_ret + (long)b * Tn;
    const float* lptr = g_lrv + (long)b * Tn;
    float* oLH = out + 0l * Bn * Tn + (long)b * Tn;
    float* oLX = out + 1l * Bn * Tn + (long)b * Tn;
    float* oZ  = out + 2l * Bn * Tn + (long)b * Tn;
    float* oU  = out + 3l * Bn * Tn + (long)b * Tn;

    float lh = 0.0f, zp = 0.0f, up = 0.0f;   // carried (enh, z, u)

    for (int t0 = 0; t0 < Tn; t0 += 64) {
        rlbuf[wv][lane] = make_float2(rptr[t0 + lane], lptr[t0 + lane]);
        asm volatile("s_waitcnt lgkmcnt(0)" ::: "memory");

        float o_lh = 0.0f, o_lx = 0.0f, o_z = 0.0f, o_u = 0.0f;

#pragma unroll 4
        for (int tm = 0; tm < 64; ++tm) {
            const float2 rl = rlbuf[wv][tm];            // uniform-addr broadcast
            const float r_t = rl.x, lrv_t = rl.y;

            float lh_t;
            if (t0 == 0 && tm == 0) {
                lh_t = lrv_t;                            // log(mean(exp(lrv0))) == lrv0
            } else {
                float s = fmaf(beta, lh, omega);
                s = fmaf(tau1, zp, s);
                s = fmaf(tau2, fmaf(zp, zp, -1.0f), s);
                lh_t = fmaf(gam, up, s);
            }

            const float z_t  = (r_t - mu) * __expf(-0.5f * lh_t);
            const float dlt  = fmaf(d2, fmaf(z_t, z_t, -1.0f), d1 * z_t);
            const float a_t  = fmaf(phi, lh_t, xi) + dlt;
            const float u_t  = lrv_t - a_t;
            const float lx_t = a_t + u_t;

            // L1: h1[j] = relu(x @ W1 + b1)
            const float h1 = fmaxf(fmaf(w12, u_t, fmaf(w11, z_t, fmaf(w10, lh_t, b1j))), 0.0f);

            // broadcast h1 as f16 through wave-local LDS (double-buffered)
            _Float16* hw = &h1f[wv][tm & 1][0];
            hw[lane] = (_Float16)h1;
            asm volatile("s_waitcnt lgkmcnt(0)" ::: "memory");

            // L2: h2[j] = relu(sum_k h1[k] * W2[k][j] + b2[j]) -- 32 dot2 insts
            const float4* h4 = (const float4*)hw;
#if HAVE_FDOT2
            float acc = 0.0f;
#pragma unroll
            for (int q = 0; q < 8; ++q) {
                const float4 v = h4[q];                  // 8 f16 (broadcast read)
                acc = __builtin_amdgcn_fdot2(__builtin_bit_cast(h2v, v.x), w2p[4 * q + 0], acc, false);
                acc = __builtin_amdgcn_fdot2(__builtin_bit_cast(h2v, v.y), w2p[4 * q + 1], acc, false);
                acc = __builtin_amdgcn_fdot2(__builtin_bit_cast(h2v, v.z), w2p[4 * q + 2], acc, false);
                acc = __builtin_amdgcn_fdot2(__builtin_bit_cast(h2v, v.w), w2p[4 * q + 3], acc, false);
            }
            const float h2s = acc;
#else
            h2v pk = {(_Float16)0.0f, (_Float16)0.0f};   // packed f16 accum (v_pk_fma_f16)
#pragma unroll
            for (int q = 0; q < 8; ++q) {
                const float4 v = h4[q];
                pk = __builtin_bit_cast(h2v, v.x) * w2p[4 * q + 0] + pk;
                pk = __builtin_bit_cast(h2v, v.y) * w2p[4 * q + 1] + pk;
                pk = __builtin_bit_cast(h2v, v.z) * w2p[4 * q + 2] + pk;
                pk = __builtin_bit_cast(h2v, v.w) * w2p[4 * q + 3] + pk;
            }
            const float h2s = (float)pk.x + (float)pk.y;
#endif
            const float h2 = fmaxf(h2s + b2j, 0.0f);

            // L3: nn = sum_j h2[j]*W3[j] + b3 (butterfly -> all lanes)
            float p = h2 * w3j;
#pragma unroll
            for (int m = 1; m < 64; m <<= 1) p += __shfl_xor(p, m, 64);
            const float nn  = p + b3s;
            const float enh = fmaf(0.01f, nn, lh_t);

            lh = enh; zp = z_t; up = u_t;

            if (lane == tm) { o_lh = enh; o_lx = lx_t; o_z = z_t; o_u = u_t; }
        }

        oLH[t0 + lane] = o_lh;
        oLX[t0 + lane] = o_lx;
        oZ [t0 + lane] = o_z;
        oU [t0 + lane] = o_u;
    }
}

extern "C" void kernel_launch(void* const* d_in, const int* in_sizes, int n_in,
                              void* d_out, int out_size, void* d_ws, size_t ws_size,
                              hipStream_t stream) {
    const float* g_ret = (const float*)d_in[0];
    const float* g_lrv = (const float*)d_in[1];
    const float* p_omega  = (const float*)d_in[2];
    const float* p_beta   = (const float*)d_in[3];
    const float* p_tau1   = (const float*)d_in[4];
    const float* p_tau2   = (const float*)d_in[5];
    const float* p_gamma  = (const float*)d_in[6];
    const float* p_xi     = (const float*)d_in[7];
    const float* p_phi    = (const float*)d_in[8];
    const float* p_delta1 = (const float*)d_in[9];
    const float* p_delta2 = (const float*)d_in[10];
    const float* p_mu     = (const float*)d_in[11];
    const float* W1 = (const float*)d_in[12];
    const float* b1 = (const float*)d_in[13];
    const float* W2 = (const float*)d_in[14];
    const float* b2 = (const float*)d_in[15];
    const float* W3 = (const float*)d_in[16];
    const float* b3 = (const float*)d_in[17];
    float* out = (float*)d_out;

    dim3 grid(Bn / WPB), block(256);
    hipLaunchKernelGGL(garch_scan_kernel, grid, block, 0, stream,
                       g_ret, g_lrv, p_omega, p_beta, p_tau1, p_tau2, p_gamma,
                       p_xi, p_phi, p_delta1, p_delta2, p_mu,
                       W1, b1, W2, b2, W3, b3, out);
}

// Round 4
// 1263.762 us; speedup vs baseline: 1.7227x; 1.1015x over previous
//
#include <hip/hip_runtime.h>

// RealizedGARCH-PINN scan. B=4096 chains, T=2048 sequential steps.
// One wave per chain; lane j owns column j of every layer.
// R4 == R3 with the DPP ctrl as a template (constant) parameter:
// DPP wave-reduce (no ds_bpermute butterfly), no hard lgkmcnt drains
// (DS is in-order per wave), 4-way split dot2 accumulator chain.

constexpr int Bn  = 4096;
constexpr int Tn  = 2048;
constexpr int WPB = 4;   // waves per block (256 threads)

typedef _Float16 h2v __attribute__((ext_vector_type(2)));

template <int CTRL>
__device__ __forceinline__ float dpp_add(float v) {
    // v += dpp_move(v, CTRL); invalid lanes contribute 0 (old = 0)
    int m = __builtin_amdgcn_update_dpp(0, __builtin_bit_cast(int, v),
                                        CTRL, 0xf, 0xf, false);
    return v + __builtin_bit_cast(float, m);
}

__device__ __forceinline__ float wave_sum_bcast(float x) {
    // canonical gfx9 full-wave sum: result lands in lane 63, then readlane
    x = dpp_add<0x111>(x);  // row_shr:1
    x = dpp_add<0x112>(x);  // row_shr:2
    x = dpp_add<0x114>(x);  // row_shr:4
    x = dpp_add<0x118>(x);  // row_shr:8
    x = dpp_add<0x142>(x);  // row_bcast:15
    x = dpp_add<0x143>(x);  // row_bcast:31
    int s = __builtin_amdgcn_readlane(__builtin_bit_cast(int, x), 63);
    return __builtin_bit_cast(float, s);   // wave-uniform (SGPR)
}

__global__ __launch_bounds__(256, 4)
void garch_scan_kernel(const float* __restrict__ g_ret,
                       const float* __restrict__ g_lrv,
                       const float* __restrict__ p_omega,
                       const float* __restrict__ p_beta,
                       const float* __restrict__ p_tau1,
                       const float* __restrict__ p_tau2,
                       const float* __restrict__ p_gamma,
                       const float* __restrict__ p_xi,
                       const float* __restrict__ p_phi,
                       const float* __restrict__ p_delta1,
                       const float* __restrict__ p_delta2,
                       const float* __restrict__ p_mu,
                       const float* __restrict__ W1,
                       const float* __restrict__ b1,
                       const float* __restrict__ W2,
                       const float* __restrict__ b2,
                       const float* __restrict__ W3,
                       const float* __restrict__ b3,
                       float* __restrict__ out)
{
    const int lane = threadIdx.x & 63;
    const int wv   = threadIdx.x >> 6;
    const int b    = blockIdx.x * WPB + wv;

    const float omega = p_omega[0], beta = p_beta[0];
    const float tau1 = p_tau1[0], tau2 = p_tau2[0], gam = p_gamma[0];
    const float xi = p_xi[0], phi = p_phi[0];
    const float d1 = p_delta1[0], d2 = p_delta2[0], mu = p_mu[0];
    const float b3s = b3[0];

    const float w10 = W1[lane], w11 = W1[64 + lane], w12 = W1[128 + lane];
    const float b1j = b1[lane], b2j = b2[lane], w3j = W3[lane];

    h2v w2p[32];
#pragma unroll
    for (int p = 0; p < 32; ++p) {
        const float a = W2[(2 * p) * 64 + lane];
        const float c = W2[(2 * p + 1) * 64 + lane];
        h2v w; w.x = (_Float16)a; w.y = (_Float16)c;
        w2p[p] = w;
    }

    __shared__ __align__(16) _Float16 h1f[WPB][2][64];  // double-buffered h1
    __shared__ float2 rlbuf[WPB][64];

    const float* rptr = g_ret + (long)b * Tn;
    const float* lptr = g_lrv + (long)b * Tn;
    float* oLH = out + 0l * Bn * Tn + (long)b * Tn;
    float* oLX = out + 1l * Bn * Tn + (long)b * Tn;
    float* oZ  = out + 2l * Bn * Tn + (long)b * Tn;
    float* oU  = out + 3l * Bn * Tn + (long)b * Tn;

    float lh = 0.0f, zp = 0.0f, up = 0.0f;
    float o_lh = 0.0f, o_lx = 0.0f, o_z = 0.0f, o_u = 0.0f;

    for (int t0 = 0; t0 < Tn; t0 += 64) {
        rlbuf[wv][lane] = make_float2(rptr[t0 + lane], lptr[t0 + lane]);
        asm volatile("" ::: "memory");   // compiler barrier; DS is in-order per wave

        auto step = [&](int tm, int buf) {
            const float2 rl = rlbuf[wv][tm];          // uniform-addr broadcast
            const float r_t = rl.x, lrv_t = rl.y;

            float lh_t;
            if (t0 == 0 && tm == 0) {
                lh_t = lrv_t;                          // log(mean(exp(lrv0))) == lrv0
            } else {
                float s = fmaf(beta, lh, omega);
                s = fmaf(tau1, zp, s);
                s = fmaf(tau2, fmaf(zp, zp, -1.0f), s);
                lh_t = fmaf(gam, up, s);
            }

            const float z_t  = (r_t - mu) * __expf(-0.5f * lh_t);
            const float dlt  = fmaf(d2, fmaf(z_t, z_t, -1.0f), d1 * z_t);
            const float a_t  = fmaf(phi, lh_t, xi) + dlt;
            const float u_t  = lrv_t - a_t;
            const float lx_t = a_t + u_t;

            const float h1 = fmaxf(fmaf(w12, u_t, fmaf(w11, z_t, fmaf(w10, lh_t, b1j))), 0.0f);

            _Float16* hw = &h1f[wv][buf][0];
            hw[lane] = (_Float16)h1;
            asm volatile("" ::: "memory");             // order write before reads (in-order DS)

            const float4* h4 = (const float4*)hw;
            float ac0 = 0.0f, ac1 = 0.0f, ac2 = 0.0f, ac3 = 0.0f;
#pragma unroll
            for (int q = 0; q < 8; ++q) {
                const float4 v = h4[q];                // broadcast ds_read_b128
                ac0 = __builtin_amdgcn_fdot2(__builtin_bit_cast(h2v, v.x), w2p[4 * q + 0], ac0, false);
                ac1 = __builtin_amdgcn_fdot2(__builtin_bit_cast(h2v, v.y), w2p[4 * q + 1], ac1, false);
                ac2 = __builtin_amdgcn_fdot2(__builtin_bit_cast(h2v, v.z), w2p[4 * q + 2], ac2, false);
                ac3 = __builtin_amdgcn_fdot2(__builtin_bit_cast(h2v, v.w), w2p[4 * q + 3], ac3, false);
            }
            const float h2 = fmaxf(((ac0 + ac1) + (ac2 + ac3)) + b2j, 0.0f);

            // L3: DPP wave reduction -> SGPR broadcast
            const float nn  = wave_sum_bcast(h2 * w3j) + b3s;
            const float enh = fmaf(0.01f, nn, lh_t);

            lh = enh; zp = z_t; up = u_t;

            if (lane == tm) { o_lh = enh; o_lx = lx_t; o_z = z_t; o_u = u_t; }
        };

        for (int tm2 = 0; tm2 < 64; tm2 += 2) {   // static double-buffer index
            step(tm2 + 0, 0);
            step(tm2 + 1, 1);
        }

        oLH[t0 + lane] = o_lh;
        oLX[t0 + lane] = o_lx;
        oZ [t0 + lane] = o_z;
        oU [t0 + lane] = o_u;
    }
}

extern "C" void kernel_launch(void* const* d_in, const int* in_sizes, int n_in,
                              void* d_out, int out_size, void* d_ws, size_t ws_size,
                              hipStream_t stream) {
    const float* g_ret = (const float*)d_in[0];
    const float* g_lrv = (const float*)d_in[1];
    const float* p_omega  = (const float*)d_in[2];
    const float* p_beta   = (const float*)d_in[3];
    const float* p_tau1   = (const float*)d_in[4];
    const float* p_tau2   = (const float*)d_in[5];
    const float* p_gamma  = (const float*)d_in[6];
    const float* p_xi     = (const float*)d_in[7];
    const float* p_phi    = (const float*)d_in[8];
    const float* p_delta1 = (const float*)d_in[9];
    const float* p_delta2 = (const float*)d_in[10];
    const float* p_mu     = (const float*)d_in[11];
    const float* W1 = (const float*)d_in[12];
    const float* b1 = (const float*)d_in[13];
    const float* W2 = (const float*)d_in[14];
    const float* b2 = (const float*)d_in[15];
    const float* W3 = (const float*)d_in[16];
    const float* b3 = (const float*)d_in[17];
    float* out = (float*)d_out;

    dim3 grid(Bn / WPB), block(256);
    hipLaunchKernelGGL(garch_scan_kernel, grid, block, 0, stream,
                       g_ret, g_lrv, p_omega, p_beta, p_tau1, p_tau2, p_gamma,
                       p_xi, p_phi, p_delta1, p_delta2, p_mu,
                       W1, b1, W2, b2, W3, b3, out);
}

// Round 5
// 1026.668 us; speedup vs baseline: 2.1205x; 1.2309x over previous
//
#include <hip/hip_runtime.h>

// RealizedGARCH-PINN scan. B=4096 chains, T=2048 sequential steps.
// R5: TWO chains per wave (lanes 0-31 = chain A, 32-63 = chain B).
// Wave-uniform scalar work, the LDS h1 broadcast, reduce, capture and
// loop overhead are amortized over 2 chains; each lane owns 2 W2 columns
// (64 packed-f16 VGPRs). 2048 waves -> 2 waves/SIMD, issue-bound regime.

constexpr int Bn  = 4096;
constexpr int Tn  = 2048;
constexpr int WPB = 4;   // waves per block (256 threads); grid = Bn/2/WPB

typedef _Float16 h2v __attribute__((ext_vector_type(2)));

template <int CTRL>
__device__ __forceinline__ float dpp_add(float v) {
    int m = __builtin_amdgcn_update_dpp(0, __builtin_bit_cast(int, v),
                                        CTRL, 0xf, 0xf, false);
    return v + __builtin_bit_cast(float, m);
}

// per-32-lane-half sum: lane31 = sum(lanes 0..31), lane63 = sum(lanes 32..63)
__device__ __forceinline__ float half_sums(float x) {
    x = dpp_add<0x111>(x);  // row_shr:1
    x = dpp_add<0x112>(x);  // row_shr:2
    x = dpp_add<0x114>(x);  // row_shr:4
    x = dpp_add<0x118>(x);  // row_shr:8
    x = dpp_add<0x142>(x);  // row_bcast:15  (adds row0->row1, row2->row3)
    return x;
}

__global__ __launch_bounds__(256, 2)
void garch_scan_kernel(const float* __restrict__ g_ret,
                       const float* __restrict__ g_lrv,
                       const float* __restrict__ p_omega,
                       const float* __restrict__ p_beta,
                       const float* __restrict__ p_tau1,
                       const float* __restrict__ p_tau2,
                       const float* __restrict__ p_gamma,
                       const float* __restrict__ p_xi,
                       const float* __restrict__ p_phi,
                       const float* __restrict__ p_delta1,
                       const float* __restrict__ p_delta2,
                       const float* __restrict__ p_mu,
                       const float* __restrict__ W1,
                       const float* __restrict__ b1,
                       const float* __restrict__ W2,
                       const float* __restrict__ b2,
                       const float* __restrict__ W3,
                       const float* __restrict__ b3,
                       float* __restrict__ out)
{
    const int lane = threadIdx.x & 63;
    const int wv   = threadIdx.x >> 6;
    const int half = lane >> 5;          // which chain within the wave
    const int l5   = lane & 31;
    const int wave_id = blockIdx.x * WPB + wv;       // 0..2047
    const long chain  = 2l * wave_id + half;         // this lane's chain

    const float omega = p_omega[0], beta = p_beta[0];
    const float tau1 = p_tau1[0], tau2 = p_tau2[0], gam = p_gamma[0];
    const float xi = p_xi[0], phi = p_phi[0];
    const float d1 = p_delta1[0], d2 = p_delta2[0], mu = p_mu[0];
    const float b3s = b3[0];

    // this lane's two W2 columns (same for both halves)
    const int c0 = 2 * l5, c1 = c0 + 1;
    const float w10a = W1[c0], w11a = W1[64 + c0], w12a = W1[128 + c0];
    const float w10b = W1[c1], w11b = W1[64 + c1], w12b = W1[128 + c1];
    const float b1a = b1[c0], b1b = b1[c1];
    const float b2a = b2[c0], b2b = b2[c1];
    const float w3a = W3[c0], w3b = W3[c1];

    h2v w2a[32], w2b[32];   // k-pairs of W2 columns c0 / c1
#pragma unroll
    for (int p = 0; p < 32; ++p) {
        const float2 r0 = *(const float2*)&W2[(2 * p) * 64 + c0];
        const float2 r1 = *(const float2*)&W2[(2 * p + 1) * 64 + c0];
        h2v wa; wa.x = (_Float16)r0.x; wa.y = (_Float16)r1.x; w2a[p] = wa;
        h2v wb; wb.x = (_Float16)r0.y; wb.y = (_Float16)r1.y; w2b[p] = wb;
    }

    __shared__ __align__(16) _Float16 h1f[WPB][2][2][64]; // [wave][buf][half][64]
    __shared__ float2 rlbuf[WPB][2][32];                  // [wave][half][step]

    const float* rptr = g_ret + chain * Tn;
    const float* lptr = g_lrv + chain * Tn;
    float* oLH = out + 0l * Bn * Tn + chain * Tn;
    float* oLX = out + 1l * Bn * Tn + chain * Tn;
    float* oZ  = out + 2l * Bn * Tn + chain * Tn;
    float* oU  = out + 3l * Bn * Tn + chain * Tn;

    float lh = 0.0f, zp = 0.0f, z2m1 = -1.0f, up = 0.0f;  // carried state
    float o_lh = 0.0f, o_lx = 0.0f, o_z = 0.0f, o_u = 0.0f;

    for (int t0 = 0; t0 < Tn; t0 += 32) {
        // stage 32 steps for both chains: lane (half,l5) loads its chain's step
        rlbuf[wv][half][l5] = make_float2(rptr[t0 + l5], lptr[t0 + l5]);
        asm volatile("" ::: "memory");   // DS is in-order per wave

        auto step = [&](int tm, int buf) {
            const float2 rl = rlbuf[wv][half][tm];   // 2-addr broadcast (free)
            const float r_t = rl.x, lrv_t = rl.y;

            float lh_t;
            if (t0 == 0 && tm == 0) {
                lh_t = lrv_t;                // log(mean(exp(lrv0))) == lrv0
            } else {
                float s = fmaf(beta, lh, omega);
                s = fmaf(tau1, zp, s);
                s = fmaf(tau2, z2m1, s);     // reuse z^2-1 from previous step
                lh_t = fmaf(gam, up, s);
            }

            const float z_t   = (r_t - mu) * __expf(-0.5f * lh_t);
            const float z2m1t = fmaf(z_t, z_t, -1.0f);
            const float dlt   = fmaf(d2, z2m1t, d1 * z_t);
            const float a_t   = fmaf(phi, lh_t, xi) + dlt;
            const float u_t   = lrv_t - a_t;
            const float lx_t  = a_t + u_t;

            // L1 for this lane's two columns
            const float h1a = fmaxf(fmaf(w12a, u_t, fmaf(w11a, z_t, fmaf(w10a, lh_t, b1a))), 0.0f);
            const float h1b = fmaxf(fmaf(w12b, u_t, fmaf(w11b, z_t, fmaf(w10b, lh_t, b1b))), 0.0f);

            // write packed pair (cols c0,c1) into this half's h1 vector
            _Float16* hw = &h1f[wv][buf][half][0];
            h2v hp; hp.x = (_Float16)h1a; hp.y = (_Float16)h1b;
            ((h2v*)hw)[l5] = hp;
            asm volatile("" ::: "memory");

            // L2: both columns against this half's full h1 (broadcast reads)
            const float4* h4 = (const float4*)hw;
            float a0 = 0.f, a1 = 0.f, a2 = 0.f, a3 = 0.f;
            float e0 = 0.f, e1 = 0.f, e2 = 0.f, e3 = 0.f;
#pragma unroll
            for (int q = 0; q < 8; ++q) {
                const float4 v = h4[q];
                const h2v p0 = __builtin_bit_cast(h2v, v.x);
                const h2v p1 = __builtin_bit_cast(h2v, v.y);
                const h2v p2 = __builtin_bit_cast(h2v, v.z);
                const h2v p3 = __builtin_bit_cast(h2v, v.w);
                a0 = __builtin_amdgcn_fdot2(p0, w2a[4 * q + 0], a0, false);
                e0 = __builtin_amdgcn_fdot2(p0, w2b[4 * q + 0], e0, false);
                a1 = __builtin_amdgcn_fdot2(p1, w2a[4 * q + 1], a1, false);
                e1 = __builtin_amdgcn_fdot2(p1, w2b[4 * q + 1], e1, false);
                a2 = __builtin_amdgcn_fdot2(p2, w2a[4 * q + 2], a2, false);
                e2 = __builtin_amdgcn_fdot2(p2, w2b[4 * q + 2], e2, false);
                a3 = __builtin_amdgcn_fdot2(p3, w2a[4 * q + 3], a3, false);
                e3 = __builtin_amdgcn_fdot2(p3, w2b[4 * q + 3], e3, false);
            }
            const float h2c0 = fmaxf(((a0 + a1) + (a2 + a3)) + b2a, 0.0f);
            const float h2c1 = fmaxf(((e0 + e1) + (e2 + e3)) + b2b, 0.0f);

            // L3 partial + per-half 32-lane reduce
            const float part = fmaf(h2c0, w3a, h2c1 * w3b);
            const float hs = half_sums(part);
            const float sA = __builtin_bit_cast(float,
                __builtin_amdgcn_readlane(__builtin_bit_cast(int, hs), 31));
            const float sB = __builtin_bit_cast(float,
                __builtin_amdgcn_readlane(__builtin_bit_cast(int, hs), 63));
            const float nn  = (half ? sB : sA) + b3s;
            const float enh = fmaf(0.01f, nn, lh_t);

            lh = enh; zp = z_t; z2m1 = z2m1t; up = u_t;

            if (l5 == tm) { o_lh = enh; o_lx = lx_t; o_z = z_t; o_u = u_t; }
        };

#pragma unroll
        for (int tm2 = 0; tm2 < 32; tm2 += 2) {   // static double-buffer index
            step(tm2 + 0, 0);
            step(tm2 + 1, 1);
        }

        oLH[t0 + l5] = o_lh;
        oLX[t0 + l5] = o_lx;
        oZ [t0 + l5] = o_z;
        oU [t0 + l5] = o_u;
    }
}

extern "C" void kernel_launch(void* const* d_in, const int* in_sizes, int n_in,
                              void* d_out, int out_size, void* d_ws, size_t ws_size,
                              hipStream_t stream) {
    const float* g_ret = (const float*)d_in[0];
    const float* g_lrv = (const float*)d_in[1];
    const float* p_omega  = (const float*)d_in[2];
    const float* p_beta   = (const float*)d_in[3];
    const float* p_tau1   = (const float*)d_in[4];
    const float* p_tau2   = (const float*)d_in[5];
    const float* p_gamma  = (const float*)d_in[6];
    const float* p_xi     = (const float*)d_in[7];
    const float* p_phi    = (const float*)d_in[8];
    const float* p_delta1 = (const float*)d_in[9];
    const float* p_delta2 = (const float*)d_in[10];
    const float* p_mu     = (const float*)d_in[11];
    const float* W1 = (const float*)d_in[12];
    const float* b1 = (const float*)d_in[13];
    const float* W2 = (const float*)d_in[14];
    const float* b2 = (const float*)d_in[15];
    const float* W3 = (const float*)d_in[16];
    const float* b3 = (const float*)d_in[17];
    float* out = (float*)d_out;

    dim3 grid(Bn / 2 / WPB), block(256);
    hipLaunchKernelGGL(garch_scan_kernel, grid, block, 0, stream,
                       g_ret, g_lrv, p_omega, p_beta, p_tau1, p_tau2, p_gamma,
                       p_xi, p_phi, p_delta1, p_delta2, p_mu,
                       W1, b1, W2, b2, W3, b3, out);
}

// Round 6
// 940.034 us; speedup vs baseline: 2.3160x; 1.0922x over previous
//
#include <hip/hip_runtime.h>

// RealizedGARCH-PINN scan. B=4096 chains, T=2048 sequential steps.
// R6: 16 chains per wave, L2 (64x64 matvec) on MFMA f32_16x16x32_f16.
// Lane l carries scalar state of chain (l&15) (4-way redundant across
// k-groups g=l>>4); A-fragment (h1) is built directly in registers in
// MFMA A-layout (row=l&15, k=8*g+j) -- no transpose, no h1 LDS staging.
// 256 waves / 256 blocks -> 1 wave per CU; latency-bound by design.

constexpr int Bn = 4096;
constexpr int Tn = 2048;

typedef _Float16 f16x8 __attribute__((ext_vector_type(8)));
typedef float    f32x4 __attribute__((ext_vector_type(4)));

template <int CTRL>
__device__ __forceinline__ float dpp_add(float v) {
    int m = __builtin_amdgcn_update_dpp(0, __builtin_bit_cast(int, v),
                                        CTRL, 0xf, 0xf, false);
    return v + __builtin_bit_cast(float, m);
}
// suffix-sum within each 16-lane row; lane (16r+15) holds that row's total
__device__ __forceinline__ float row16_sum(float x) {
    x = dpp_add<0x111>(x);  // row_shr:1
    x = dpp_add<0x112>(x);  // row_shr:2
    x = dpp_add<0x114>(x);  // row_shr:4
    x = dpp_add<0x118>(x);  // row_shr:8
    return x;
}

__global__ __launch_bounds__(64, 1)
void garch_scan_kernel(const float* __restrict__ g_ret,
                       const float* __restrict__ g_lrv,
                       const float* __restrict__ p_omega,
                       const float* __restrict__ p_beta,
                       const float* __restrict__ p_tau1,
                       const float* __restrict__ p_tau2,
                       const float* __restrict__ p_gamma,
                       const float* __restrict__ p_xi,
                       const float* __restrict__ p_phi,
                       const float* __restrict__ p_delta1,
                       const float* __restrict__ p_delta2,
                       const float* __restrict__ p_mu,
                       const float* __restrict__ W1,
                       const float* __restrict__ b1,
                       const float* __restrict__ W2,
                       const float* __restrict__ b2,
                       const float* __restrict__ W3,
                       const float* __restrict__ b3,
                       float* __restrict__ out)
{
    const int l = threadIdx.x;      // 0..63
    const int c = l & 15;           // this lane's chain (within block)
    const int g = l >> 4;           // k-slice group
    const long cb = (long)blockIdx.x * 16;

    const float omega = p_omega[0], beta = p_beta[0];
    const float tau1 = p_tau1[0], tau2 = p_tau2[0], gam = p_gamma[0];
    const float xi = p_xi[0], phi = p_phi[0];
    const float d1 = p_delta1[0], d2 = p_delta2[0], mu = p_mu[0];
    const float b3s = b3[0];

    // W1/b1 slices for this lane's k-positions kk = 32*kt + 8*g + j
    float w1x[2][8], w1y[2][8], w1z[2][8], b1s[2][8];
#pragma unroll
    for (int kt = 0; kt < 2; ++kt)
#pragma unroll
        for (int j = 0; j < 8; ++j) {
            const int kk = 32 * kt + 8 * g + j;
            w1x[kt][j] = W1[kk];
            w1y[kt][j] = W1[64 + kk];
            w1z[kt][j] = W1[128 + kk];
            b1s[kt][j] = b1[kk];
        }

    // W2 B-fragments: B[k][col], lane holds k=32*kt+8*g+j, col=16*ct+c
    f16x8 bf[2][4];
#pragma unroll
    for (int kt = 0; kt < 2; ++kt)
#pragma unroll
        for (int ct = 0; ct < 4; ++ct)
#pragma unroll
            for (int j = 0; j < 8; ++j)
                bf[kt][ct][j] = (_Float16)W2[(32 * kt + 8 * g + j) * 64 + 16 * ct + c];

    float b2s[4], w3s[4];
#pragma unroll
    for (int ct = 0; ct < 4; ++ct) {
        b2s[ct] = b2[16 * ct + c];
        w3s[ct] = W3[16 * ct + c];
    }

    __shared__ float4 nnbuf[4];                       // per-chain nn sums
    __shared__ __align__(16) float ldsout[4][16][68]; // [arr][chain][t&63]

    const float* rp = g_ret + (cb + c) * Tn;
    const float* lp = g_lrv + (cb + c) * Tn;

    float lh = 0.0f, zp = 0.0f, z2m1 = -1.0f, up = 0.0f;  // chain state
    float rn = rp[0], ln = lp[0];                          // prefetched inputs

    for (int t0 = 0; t0 < Tn; t0 += 64) {
#pragma unroll 4
        for (int tw = 0; tw < 64; ++tw) {
            const int t = t0 + tw;
            const float r_t = rn, lrv_t = ln;
            const int tn1 = (t + 1 < Tn) ? t + 1 : t;   // prefetch next step
            rn = rp[tn1]; ln = lp[tn1];

            float s = fmaf(beta, lh, omega);
            s = fmaf(tau1, zp, s);
            s = fmaf(tau2, z2m1, s);
            s = fmaf(gam, up, s);
            const float lh_t = (t == 0) ? lrv_t : s;    // lh0 = lrv0

            const float z_t  = (r_t - mu) * __expf(-0.5f * lh_t);
            const float z2n  = fmaf(z_t, z_t, -1.0f);
            const float dlt  = fmaf(d2, z2n, d1 * z_t);
            const float a_t  = fmaf(phi, lh_t, xi) + dlt;
            const float u_t  = lrv_t - a_t;
            const float lx_t = a_t + u_t;

            // A-fragments: h1[chain c][k-slice] directly in MFMA layout
            f16x8 af0, af1;
#pragma unroll
            for (int j = 0; j < 8; ++j) {
                const float ha = fmaf(w1z[0][j], u_t,
                                  fmaf(w1y[0][j], z_t,
                                   fmaf(w1x[0][j], lh_t, b1s[0][j])));
                af0[j] = (_Float16)fmaxf(ha, 0.0f);
                const float hb = fmaf(w1z[1][j], u_t,
                                  fmaf(w1y[1][j], z_t,
                                   fmaf(w1x[1][j], lh_t, b1s[1][j])));
                af1[j] = (_Float16)fmaxf(hb, 0.0f);
            }

            // L2: h2pre[16 chains x 64 cols] = h1 @ W2 (8 MFMA)
            f32x4 acc[4];
#pragma unroll
            for (int ct = 0; ct < 4; ++ct) {
                f32x4 z4 = {0.0f, 0.0f, 0.0f, 0.0f};
                z4 = __builtin_amdgcn_mfma_f32_16x16x32_f16(af0, bf[0][ct], z4, 0, 0, 0);
                acc[ct] = __builtin_amdgcn_mfma_f32_16x16x32_f16(af1, bf[1][ct], z4, 0, 0, 0);
            }

            // L3 partials: pp[i] for chain 4g+i, this lane's cols 16*ct+c
            float pp0 = 0.f, pp1 = 0.f, pp2 = 0.f, pp3 = 0.f;
#pragma unroll
            for (int ct = 0; ct < 4; ++ct) {
                pp0 = fmaf(fmaxf(acc[ct][0] + b2s[ct], 0.0f), w3s[ct], pp0);
                pp1 = fmaf(fmaxf(acc[ct][1] + b2s[ct], 0.0f), w3s[ct], pp1);
                pp2 = fmaf(fmaxf(acc[ct][2] + b2s[ct], 0.0f), w3s[ct], pp2);
                pp3 = fmaf(fmaxf(acc[ct][3] + b2s[ct], 0.0f), w3s[ct], pp3);
            }
            // reduce over the 16 lanes of this row (cols) -> lane 16g+15
            pp0 = row16_sum(pp0);
            pp1 = row16_sum(pp1);
            pp2 = row16_sum(pp2);
            pp3 = row16_sum(pp3);

            if (c == 15) nnbuf[g] = make_float4(pp0, pp1, pp2, pp3);
            asm volatile("" ::: "memory");   // DS in-order within wave
            const float nn = ((const float*)nnbuf)[c] + b3s;

            const float enh = fmaf(0.01f, nn, lh_t);
            lh = enh; zp = z_t; z2m1 = z2n; up = u_t;

            // stage this step's outputs (all 4 copies write same value)
            ldsout[0][c][tw] = enh;
            ldsout[1][c][tw] = lx_t;
            ldsout[2][c][tw] = z_t;
            ldsout[3][c][tw] = u_t;
        }

        asm volatile("" ::: "memory");
        // drain: lane l -> chain cd=l>>2, t-block tb=l&3 (16 steps each)
        const int  cd = l >> 2, tb = l & 3;
        const long chd = cb + cd;
#pragma unroll
        for (int a = 0; a < 4; ++a) {
            float* oa = out + (long)a * Bn * Tn + chd * Tn + t0 + 16 * tb;
#pragma unroll
            for (int i = 0; i < 4; ++i) {
                const float4 v = *(const float4*)&ldsout[a][cd][16 * tb + 4 * i];
                *(float4*)&oa[4 * i] = v;
            }
        }
    }
}

extern "C" void kernel_launch(void* const* d_in, const int* in_sizes, int n_in,
                              void* d_out, int out_size, void* d_ws, size_t ws_size,
                              hipStream_t stream) {
    const float* g_ret = (const float*)d_in[0];
    const float* g_lrv = (const float*)d_in[1];
    const float* p_omega  = (const float*)d_in[2];
    const float* p_beta   = (const float*)d_in[3];
    const float* p_tau1   = (const float*)d_in[4];
    const float* p_tau2   = (const float*)d_in[5];
    const float* p_gamma  = (const float*)d_in[6];
    const float* p_xi     = (const float*)d_in[7];
    const float* p_phi    = (const float*)d_in[8];
    const float* p_delta1 = (const float*)d_in[9];
    const float* p_delta2 = (const float*)d_in[10];
    const float* p_mu     = (const float*)d_in[11];
    const float* W1 = (const float*)d_in[12];
    const float* b1 = (const float*)d_in[13];
    const float* W2 = (const float*)d_in[14];
    const float* b2 = (const float*)d_in[15];
    const float* W3 = (const float*)d_in[16];
    const float* b3 = (const float*)d_in[17];
    float* out = (float*)d_out;

    dim3 grid(Bn / 16), block(64);
    hipLaunchKernelGGL(garch_scan_kernel, grid, block, 0, stream,
                       g_ret, g_lrv, p_omega, p_beta, p_tau1, p_tau2, p_gamma,
                       p_xi, p_phi, p_delta1, p_delta2, p_mu,
                       W1, b1, W2, b2, W3, b3, out);
}

// Round 7
// 749.777 us; speedup vs baseline: 2.9037x; 1.2538x over previous
//
#include <hip/hip_runtime.h>

// RealizedGARCH-PINN scan. B=4096 chains, T=2048 sequential steps.
// R7: 16 chains/wave, MFMA L2, per-step instruction surgery:
//  - A-build (L1) in packed f16 (v_pk_fma_f16), ~35 insts vs ~80
//  - b2 folded into MFMA C-init
//  - all-DPP reduce (quad_perm xor + row_ror) + 1 ds_bpermute for nn
//    (replaces LDS round-trip on the recurrence critical path)
//  - inputs staged per-64-step chunk in padded LDS (2 ds_read/step)
// 256 blocks x 1 wave; issue-bound on 1 SIMD/CU by design.

constexpr int Bn = 4096;
constexpr int Tn = 2048;

typedef _Float16 h2v   __attribute__((ext_vector_type(2)));
typedef _Float16 f16x8 __attribute__((ext_vector_type(8)));
typedef float    f32x4 __attribute__((ext_vector_type(4)));

template <int CTRL>
__device__ __forceinline__ float dpp_mov(float v) {
    int m = __builtin_amdgcn_update_dpp(0, __builtin_bit_cast(int, v),
                                        CTRL, 0xf, 0xf, false);
    return __builtin_bit_cast(float, m);
}

__global__ __launch_bounds__(64, 1)
void garch_scan_kernel(const float* __restrict__ g_ret,
                       const float* __restrict__ g_lrv,
                       const float* __restrict__ p_omega,
                       const float* __restrict__ p_beta,
                       const float* __restrict__ p_tau1,
                       const float* __restrict__ p_tau2,
                       const float* __restrict__ p_gamma,
                       const float* __restrict__ p_xi,
                       const float* __restrict__ p_phi,
                       const float* __restrict__ p_delta1,
                       const float* __restrict__ p_delta2,
                       const float* __restrict__ p_mu,
                       const float* __restrict__ W1,
                       const float* __restrict__ b1,
                       const float* __restrict__ W2,
                       const float* __restrict__ b2,
                       const float* __restrict__ W3,
                       const float* __restrict__ b3,
                       float* __restrict__ out)
{
    const int l = threadIdx.x;      // 0..63
    const int c = l & 15;           // chain (within block) / A-row / C-col
    const int g = l >> 4;           // k-slice group
    const long cb = (long)blockIdx.x * 16;

    const float omega = p_omega[0], beta = p_beta[0];
    const float tau1 = p_tau1[0], tau2 = p_tau2[0], gam = p_gamma[0];
    const float xi = p_xi[0], phi = p_phi[0];
    const float d1 = p_delta1[0], d2 = p_delta2[0], mu = p_mu[0];
    const float b3s = b3[0];

    // W1/b1 as packed f16 pairs over this lane's k-positions
    // pair q = 4*kt + jp covers k = 32*kt + 8*g + 2*jp (+1)
    h2v w1xp[8], w1yp[8], w1zp[8], b1p[8];
#pragma unroll
    for (int q = 0; q < 8; ++q) {
        const int kt = q >> 2, jp = q & 3;
        const int k0 = 32 * kt + 8 * g + 2 * jp;
        h2v a;
        a.x = (_Float16)W1[k0];        a.y = (_Float16)W1[k0 + 1];        w1xp[q] = a;
        a.x = (_Float16)W1[64 + k0];   a.y = (_Float16)W1[64 + k0 + 1];   w1yp[q] = a;
        a.x = (_Float16)W1[128 + k0];  a.y = (_Float16)W1[128 + k0 + 1];  w1zp[q] = a;
        a.x = (_Float16)b1[k0];        a.y = (_Float16)b1[k0 + 1];        b1p[q] = a;
    }

    // W2 B-fragments: B[k=32*kt+8*g+j][col=16*ct+c]
    f16x8 bfr[2][4];
#pragma unroll
    for (int kt = 0; kt < 2; ++kt)
#pragma unroll
        for (int ct = 0; ct < 4; ++ct)
#pragma unroll
            for (int j = 0; j < 8; ++j)
                bfr[kt][ct][j] = (_Float16)W2[(32 * kt + 8 * g + j) * 64 + 16 * ct + c];

    // b2 folded into MFMA C-init (col = 16*ct + c, same for all rows)
    f32x4 binit[4];
    float w3s[4];
#pragma unroll
    for (int ct = 0; ct < 4; ++ct) {
        const float bv = b2[16 * ct + c];
        f32x4 z4 = {bv, bv, bv, bv};
        binit[ct] = z4;
        w3s[ct] = W3[16 * ct + c];
    }

    // bpermute source for nn: dest lane (g',c') pulls chain c' from
    // lane 16*(c'>>2) + (c'&3) (which holds chain 4g+(c&3) = c')
    const int nn_idx = ((c >> 2) * 16 + (c & 3)) * 4;

    __shared__ __align__(16) float lds_rl[2][16][68];   // staged (r, lrv)
    __shared__ __align__(16) float ldsout[4][16][68];   // output staging

    const float* rbase = g_ret + cb * Tn;
    const float* lbase = g_lrv + cb * Tn;

    float lh = 0.0f, zp = 0.0f, z2m1 = -1.0f, up = 0.0f;  // chain state
    const h2v hzero = {(_Float16)0.0f, (_Float16)0.0f};

    for (int t0 = 0; t0 < Tn; t0 += 64) {
        // ---- stage 64 steps of (r, lrv) for all 16 chains ----
        float tr[16], tl[16];
#pragma unroll
        for (int k = 0; k < 16; ++k) {
            tr[k] = rbase[(long)k * Tn + t0 + l];
            tl[k] = lbase[(long)k * Tn + t0 + l];
        }
#pragma unroll
        for (int k = 0; k < 16; ++k) {
            lds_rl[0][k][l] = tr[k];
            lds_rl[1][k][l] = tl[k];
        }
        asm volatile("" ::: "memory");   // DS in-order within wave

#pragma unroll 4
        for (int tw = 0; tw < 64; ++tw) {
            const float r_t   = lds_rl[0][c][tw];
            const float lrv_t = lds_rl[1][c][tw];

            float s = fmaf(beta, lh, omega);
            s = fmaf(tau1, zp, s);
            s = fmaf(tau2, z2m1, s);
            s = fmaf(gam, up, s);
            const float lh_t = (t0 + tw == 0) ? lrv_t : s;  // lh0 = lrv0

            const float z_t  = (r_t - mu) * __expf(-0.5f * lh_t);
            const float z2n  = fmaf(z_t, z_t, -1.0f);
            const float dlt  = fmaf(d2, z2n, d1 * z_t);
            const float a_t  = fmaf(phi, lh_t, xi) + dlt;
            const float u_t  = lrv_t - a_t;
            const float lx_t = a_t + u_t;

            // ---- L1 in packed f16: h1 pairs in MFMA A-layout ----
            const h2v lh2 = __builtin_bit_cast(h2v, __builtin_amdgcn_cvt_pkrtz(lh_t, lh_t));
            const h2v zz2 = __builtin_bit_cast(h2v, __builtin_amdgcn_cvt_pkrtz(z_t,  z_t));
            const h2v uu2 = __builtin_bit_cast(h2v, __builtin_amdgcn_cvt_pkrtz(u_t,  u_t));

            union AF { h2v p[4]; f16x8 v; } a0, a1;
#pragma unroll
            for (int jp = 0; jp < 4; ++jp) {
                h2v h = w1xp[jp] * lh2 + b1p[jp];
                h = w1yp[jp] * zz2 + h;
                h = w1zp[jp] * uu2 + h;
                a0.p[jp] = __builtin_elementwise_max(h, hzero);
                h = w1xp[4 + jp] * lh2 + b1p[4 + jp];
                h = w1yp[4 + jp] * zz2 + h;
                h = w1zp[4 + jp] * uu2 + h;
                a1.p[jp] = __builtin_elementwise_max(h, hzero);
            }

            // ---- L2: 8 MFMA, C-init = b2 ----
            f32x4 acc[4];
#pragma unroll
            for (int ct = 0; ct < 4; ++ct) {
                f32x4 t4 = __builtin_amdgcn_mfma_f32_16x16x32_f16(a0.v, bfr[0][ct], binit[ct], 0, 0, 0);
                acc[ct]  = __builtin_amdgcn_mfma_f32_16x16x32_f16(a1.v, bfr[1][ct], t4, 0, 0, 0);
            }

            // ---- L3 partials: pp[i] = chain 4g+i, this lane's 4 cols ----
            float pp0 = 0.f, pp1 = 0.f, pp2 = 0.f, pp3 = 0.f;
#pragma unroll
            for (int ct = 0; ct < 4; ++ct) {
                pp0 = fmaf(fmaxf(acc[ct][0], 0.0f), w3s[ct], pp0);
                pp1 = fmaf(fmaxf(acc[ct][1], 0.0f), w3s[ct], pp1);
                pp2 = fmaf(fmaxf(acc[ct][2], 0.0f), w3s[ct], pp2);
                pp3 = fmaf(fmaxf(acc[ct][3], 0.0f), w3s[ct], pp3);
            }

            // ---- all-DPP reduce: quad transpose-reduce, then sum quads ----
            const bool o1 = (c & 1) != 0, o2 = (c & 2) != 0;
            float v01 = o1 ? pp1 : pp0, q01 = o1 ? pp0 : pp1;
            v01 += dpp_mov<0xB1>(q01);            // quad_perm xor1
            float v23 = o1 ? pp3 : pp2, q23 = o1 ? pp2 : pp3;
            v23 += dpp_mov<0xB1>(q23);
            float w  = o2 ? v23 : v01, qw = o2 ? v01 : v23;
            w += dpp_mov<0x4E>(qw);               // quad_perm xor2
            w += dpp_mov<0x124>(w);               // row_ror:4
            w += dpp_mov<0x128>(w);               // row_ror:8
            // lane (g,c) now holds nn for chain 4g+(c&3); route chain c here
            const float nn = __builtin_bit_cast(float,
                __builtin_amdgcn_ds_bpermute(nn_idx, __builtin_bit_cast(int, w))) + b3s;

            const float enh = fmaf(0.01f, nn, lh_t);

            ldsout[0][c][tw] = enh;
            ldsout[1][c][tw] = lx_t;
            ldsout[2][c][tw] = z_t;
            ldsout[3][c][tw] = u_t;

            lh = enh; zp = z_t; z2m1 = z2n; up = u_t;
        }

        asm volatile("" ::: "memory");
        // ---- drain: lane -> chain cd=l>>2, 16-step block tb=l&3 ----
        const int  cd = l >> 2, tb = l & 3;
        const long chd = cb + cd;
#pragma unroll
        for (int a = 0; a < 4; ++a) {
            float* oa = out + (long)a * Bn * Tn + chd * Tn + t0 + 16 * tb;
#pragma unroll
            for (int i = 0; i < 4; ++i) {
                const float4 v = *(const float4*)&ldsout[a][cd][16 * tb + 4 * i];
                *(float4*)&oa[4 * i] = v;
            }
        }
    }
}

extern "C" void kernel_launch(void* const* d_in, const int* in_sizes, int n_in,
                              void* d_out, int out_size, void* d_ws, size_t ws_size,
                              hipStream_t stream) {
    const float* g_ret = (const float*)d_in[0];
    const float* g_lrv = (const float*)d_in[1];
    const float* p_omega  = (const float*)d_in[2];
    const float* p_beta   = (const float*)d_in[3];
    const float* p_tau1   = (const float*)d_in[4];
    const float* p_tau2   = (const float*)d_in[5];
    const float* p_gamma  = (const float*)d_in[6];
    const float* p_xi     = (const float*)d_in[7];
    const float* p_phi    = (const float*)d_in[8];
    const float* p_delta1 = (const float*)d_in[9];
    const float* p_delta2 = (const float*)d_in[10];
    const float* p_mu     = (const float*)d_in[11];
    const float* W1 = (const float*)d_in[12];
    const float* b1 = (const float*)d_in[13];
    const float* W2 = (const float*)d_in[14];
    const float* b2 = (const float*)d_in[15];
    const float* W3 = (const float*)d_in[16];
    const float* b3 = (const float*)d_in[17];
    float* out = (float*)d_out;

    dim3 grid(Bn / 16), block(64);
    hipLaunchKernelGGL(garch_scan_kernel, grid, block, 0, stream,
                       g_ret, g_lrv, p_omega, p_beta, p_tau1, p_tau2, p_gamma,
                       p_xi, p_phi, p_delta1, p_delta2, p_mu,
                       W1, b1, W2, b2, W3, b3, out);
}

// Round 8
// 700.654 us; speedup vs baseline: 3.1072x; 1.0701x over previous
//
#include <hip/hip_runtime.h>

// RealizedGARCH-PINN scan. B=4096 chains, T=2048 sequential steps.
// R8: 16 chains/wave, MFMA L2. Codegen surgery vs R7:
//  - A-fragment assembled via shufflevector pair-concat (no union)
//  - L3 partials in packed f16 (cvt_pkrtz + pk_max + fdot2): 24 insts
//  - 1 ds_read_b64 (interleaved inputs) + 2 ds_write_b64 (packed outs)
//  - recurrence reassociated to 3-deep tree
// 256 blocks x 1 wave; issue/latency-bound on 1 SIMD per CU.

constexpr int Bn = 4096;
constexpr int Tn = 2048;

typedef _Float16 h2v   __attribute__((ext_vector_type(2)));
typedef _Float16 f16x4 __attribute__((ext_vector_type(4)));
typedef _Float16 f16x8 __attribute__((ext_vector_type(8)));
typedef float    f32x4 __attribute__((ext_vector_type(4)));

template <int CTRL>
__device__ __forceinline__ float dpp_mov(float v) {
    int m = __builtin_amdgcn_update_dpp(0, __builtin_bit_cast(int, v),
                                        CTRL, 0xf, 0xf, false);
    return __builtin_bit_cast(float, m);
}

__global__ __launch_bounds__(64, 1)
void garch_scan_kernel(const float* __restrict__ g_ret,
                       const float* __restrict__ g_lrv,
                       const float* __restrict__ p_omega,
                       const float* __restrict__ p_beta,
                       const float* __restrict__ p_tau1,
                       const float* __restrict__ p_tau2,
                       const float* __restrict__ p_gamma,
                       const float* __restrict__ p_xi,
                       const float* __restrict__ p_phi,
                       const float* __restrict__ p_delta1,
                       const float* __restrict__ p_delta2,
                       const float* __restrict__ p_mu,
                       const float* __restrict__ W1,
                       const float* __restrict__ b1,
                       const float* __restrict__ W2,
                       const float* __restrict__ b2,
                       const float* __restrict__ W3,
                       const float* __restrict__ b3,
                       float* __restrict__ out)
{
    const int l = threadIdx.x;      // 0..63
    const int c = l & 15;           // chain (within block) / A-row / C-col
    const int g = l >> 4;           // k-slice group
    const long cb = (long)blockIdx.x * 16;

    const float omega = p_omega[0], beta = p_beta[0];
    const float tau1 = p_tau1[0], tau2 = p_tau2[0], gam = p_gamma[0];
    const float xi = p_xi[0], phi = p_phi[0];
    const float d1 = p_delta1[0], d2 = p_delta2[0], mu = p_mu[0];
    const float b3s = b3[0];

    // W1/b1 packed f16 pairs; pair q = 4*kt + jp covers k = 32*kt + 8*g + 2*jp
    h2v w1xp[8], w1yp[8], w1zp[8], b1p[8];
#pragma unroll
    for (int q = 0; q < 8; ++q) {
        const int kt = q >> 2, jp = q & 3;
        const int k0 = 32 * kt + 8 * g + 2 * jp;
        h2v a;
        a.x = (_Float16)W1[k0];        a.y = (_Float16)W1[k0 + 1];        w1xp[q] = a;
        a.x = (_Float16)W1[64 + k0];   a.y = (_Float16)W1[64 + k0 + 1];   w1yp[q] = a;
        a.x = (_Float16)W1[128 + k0];  a.y = (_Float16)W1[128 + k0 + 1];  w1zp[q] = a;
        a.x = (_Float16)b1[k0];        a.y = (_Float16)b1[k0 + 1];        b1p[q] = a;
    }

    // W2 B-fragments: B[k=32*kt+8*g+j][col=16*ct+c]
    f16x8 bfr[2][4];
#pragma unroll
    for (int kt = 0; kt < 2; ++kt)
#pragma unroll
        for (int ct = 0; ct < 4; ++ct)
#pragma unroll
            for (int j = 0; j < 8; ++j)
                bfr[kt][ct][j] = (_Float16)W2[(32 * kt + 8 * g + j) * 64 + 16 * ct + c];

    // b2 folded into MFMA C-init (col = 16*ct + c)
    f32x4 binit[4];
#pragma unroll
    for (int ct = 0; ct < 4; ++ct) {
        const float bv = b2[16 * ct + c];
        f32x4 z4 = {bv, bv, bv, bv};
        binit[ct] = z4;
    }
    // W3 packed pairs: (w3[c], w3[16+c]) and (w3[32+c], w3[48+c])
    h2v w3p01, w3p23;
    w3p01.x = (_Float16)W3[c];      w3p01.y = (_Float16)W3[16 + c];
    w3p23.x = (_Float16)W3[32 + c]; w3p23.y = (_Float16)W3[48 + c];

    // bpermute source: chain c's nn lives in lane 16*(c>>2) + (c&3)
    const int nn_idx = ((c >> 2) * 16 + (c & 3)) * 4;

    __shared__ __align__(16) float2 lds_in[16][66];   // (r, lrv) per chain/step
    __shared__ __align__(16) float2 ldsA[16][66];     // (enh, lx)
    __shared__ __align__(16) float2 ldsB[16][66];     // (z, u)

    const float* rbase = g_ret + cb * Tn;
    const float* lbase = g_lrv + cb * Tn;

    float lh = 0.0f, zp = 0.0f, z2m1 = -1.0f, up = 0.0f;  // chain state
    const h2v hzero = {(_Float16)0.0f, (_Float16)0.0f};

    for (int t0 = 0; t0 < Tn; t0 += 64) {
        // ---- stage 64 steps of (r, lrv) for all 16 chains, interleaved ----
        {
            float tr[16], tl[16];
#pragma unroll
            for (int k = 0; k < 16; ++k) {
                tr[k] = rbase[(long)k * Tn + t0 + l];
                tl[k] = lbase[(long)k * Tn + t0 + l];
            }
#pragma unroll
            for (int k = 0; k < 16; ++k)
                lds_in[k][l] = make_float2(tr[k], tl[k]);
        }
        asm volatile("" ::: "memory");   // DS in-order within wave

#pragma unroll 4
        for (int tw = 0; tw < 64; ++tw) {
            const float2 rl = lds_in[c][tw];
            const float r_t = rl.x, lrv_t = rl.y;

            // recurrence (3-deep tree)
            const float sA = fmaf(beta, lh, omega);
            const float sB = fmaf(tau2, z2m1, tau1 * zp);
            const float sC = fmaf(gam, up, sA + sB);
            const float lh_t = (t0 + tw == 0) ? lrv_t : sC;  // lh0 = lrv0

            const float z_t  = (r_t - mu) * __expf(-0.5f * lh_t);
            const float z2n  = fmaf(z_t, z_t, -1.0f);
            const float dlt  = fmaf(d2, z2n, d1 * z_t);
            const float a_t  = fmaf(phi, lh_t, xi) + dlt;
            const float u_t  = lrv_t - a_t;
            const float lx_t = a_t + u_t;

            // ---- L1 packed f16: h1 pairs in MFMA A-layout ----
            const h2v lh2 = __builtin_bit_cast(h2v, __builtin_amdgcn_cvt_pkrtz(lh_t, lh_t));
            const h2v zz2 = __builtin_bit_cast(h2v, __builtin_amdgcn_cvt_pkrtz(z_t,  z_t));
            const h2v uu2 = __builtin_bit_cast(h2v, __builtin_amdgcn_cvt_pkrtz(u_t,  u_t));

            h2v q[8];
#pragma unroll
            for (int p = 0; p < 8; ++p) {
                h2v h = w1xp[p] * lh2 + b1p[p];
                h = w1yp[p] * zz2 + h;
                h = w1zp[p] * uu2 + h;
                q[p] = __builtin_elementwise_max(h, hzero);
            }
            const f16x4 lo0 = __builtin_shufflevector(q[0], q[1], 0, 1, 2, 3);
            const f16x4 hi0 = __builtin_shufflevector(q[2], q[3], 0, 1, 2, 3);
            const f16x8 a0  = __builtin_shufflevector(lo0, hi0, 0, 1, 2, 3, 4, 5, 6, 7);
            const f16x4 lo1 = __builtin_shufflevector(q[4], q[5], 0, 1, 2, 3);
            const f16x4 hi1 = __builtin_shufflevector(q[6], q[7], 0, 1, 2, 3);
            const f16x8 a1  = __builtin_shufflevector(lo1, hi1, 0, 1, 2, 3, 4, 5, 6, 7);

            // ---- L2: 8 MFMA, C-init = b2 ----
            f32x4 acc[4];
#pragma unroll
            for (int ct = 0; ct < 4; ++ct) {
                f32x4 t4 = __builtin_amdgcn_mfma_f32_16x16x32_f16(a0, bfr[0][ct], binit[ct], 0, 0, 0);
                acc[ct]  = __builtin_amdgcn_mfma_f32_16x16x32_f16(a1, bfr[1][ct], t4, 0, 0, 0);
            }

            // ---- L3 partials in packed f16: pp[i] for chain 4g+i ----
            float pp[4];
#pragma unroll
            for (int i = 0; i < 4; ++i) {
                h2v p01, p23;
                p01 = __builtin_bit_cast(h2v, __builtin_amdgcn_cvt_pkrtz(acc[0][i], acc[1][i]));
                p23 = __builtin_bit_cast(h2v, __builtin_amdgcn_cvt_pkrtz(acc[2][i], acc[3][i]));
                p01 = __builtin_elementwise_max(p01, hzero);
                p23 = __builtin_elementwise_max(p23, hzero);
                pp[i] = __builtin_amdgcn_fdot2(p01, w3p01,
                          __builtin_amdgcn_fdot2(p23, w3p23, 0.0f, false), false);
            }

            // ---- all-DPP reduce (quad transpose + row_ror), then route ----
            const bool o1 = (c & 1) != 0, o2 = (c & 2) != 0;
            float v01 = o1 ? pp[1] : pp[0], q01 = o1 ? pp[0] : pp[1];
            v01 += dpp_mov<0xB1>(q01);            // quad_perm xor1
            float v23 = o1 ? pp[3] : pp[2], q23 = o1 ? pp[2] : pp[3];
            v23 += dpp_mov<0xB1>(q23);
            float w  = o2 ? v23 : v01, qw = o2 ? v01 : v23;
            w += dpp_mov<0x4E>(qw);               // quad_perm xor2
            w += dpp_mov<0x124>(w);               // row_ror:4
            w += dpp_mov<0x128>(w);               // row_ror:8
            const float nn = __builtin_bit_cast(float,
                __builtin_amdgcn_ds_bpermute(nn_idx, __builtin_bit_cast(int, w))) + b3s;

            const float enh = fmaf(0.01f, nn, lh_t);

            ldsA[c][tw] = make_float2(enh, lx_t);
            ldsB[c][tw] = make_float2(z_t, u_t);

            lh = enh; zp = z_t; z2m1 = z2n; up = u_t;
        }

        asm volatile("" ::: "memory");
        // ---- drain: lane -> chain cd=l>>2, 16-step block tb=l&3 ----
        const int  cd = l >> 2, tb = l & 3;
        const long chd = cb + cd;
        float* oLH = out + 0l * Bn * Tn + chd * Tn + t0 + 16 * tb;
        float* oLX = out + 1l * Bn * Tn + chd * Tn + t0 + 16 * tb;
        float* oZ  = out + 2l * Bn * Tn + chd * Tn + t0 + 16 * tb;
        float* oU  = out + 3l * Bn * Tn + chd * Tn + t0 + 16 * tb;
#pragma unroll
        for (int i = 0; i < 4; ++i) {
            const float4 pA01 = *(const float4*)&ldsA[cd][16 * tb + 4 * i];
            const float4 pA23 = *(const float4*)&ldsA[cd][16 * tb + 4 * i + 2];
            const float4 pB01 = *(const float4*)&ldsB[cd][16 * tb + 4 * i];
            const float4 pB23 = *(const float4*)&ldsB[cd][16 * tb + 4 * i + 2];
            *(float4*)&oLH[4 * i] = make_float4(pA01.x, pA01.z, pA23.x, pA23.z);
            *(float4*)&oLX[4 * i] = make_float4(pA01.y, pA01.w, pA23.y, pA23.w);
            *(float4*)&oZ [4 * i] = make_float4(pB01.x, pB01.z, pB23.x, pB23.z);
            *(float4*)&oU [4 * i] = make_float4(pB01.y, pB01.w, pB23.y, pB23.w);
        }
    }
}

extern "C" void kernel_launch(void* const* d_in, const int* in_sizes, int n_in,
                              void* d_out, int out_size, void* d_ws, size_t ws_size,
                              hipStream_t stream) {
    const float* g_ret = (const float*)d_in[0];
    const float* g_lrv = (const float*)d_in[1];
    const float* p_omega  = (const float*)d_in[2];
    const float* p_beta   = (const float*)d_in[3];
    const float* p_tau1   = (const float*)d_in[4];
    const float* p_tau2   = (const float*)d_in[5];
    const float* p_gamma  = (const float*)d_in[6];
    const float* p_xi     = (const float*)d_in[7];
    const float* p_phi    = (const float*)d_in[8];
    const float* p_delta1 = (const float*)d_in[9];
    const float* p_delta2 = (const float*)d_in[10];
    const float* p_mu     = (const float*)d_in[11];
    const float* W1 = (const float*)d_in[12];
    const float* b1 = (const float*)d_in[13];
    const float* W2 = (const float*)d_in[14];
    const float* b2 = (const float*)d_in[15];
    const float* W3 = (const float*)d_in[16];
    const float* b3 = (const float*)d_in[17];
    float* out = (float*)d_out;

    dim3 grid(Bn / 16), block(64);
    hipLaunchKernelGGL(garch_scan_kernel, grid, block, 0, stream,
                       g_ret, g_lrv, p_omega, p_beta, p_tau1, p_tau2, p_gamma,
                       p_xi, p_phi, p_delta1, p_delta2, p_mu,
                       W1, b1, W2, b2, W3, b3, out);
}

// Round 10
// 667.663 us; speedup vs baseline: 3.2608x; 1.0494x over previous
//
#include <hip/hip_runtime.h>

// RealizedGARCH-PINN scan. B=4096 chains, T=2048 sequential steps.
// R10 == R9 with permlane32_swap return indexed as a vector (r2[0]/r2[1]).
// 16 chains/wave, MFMA L2 with SWAPPED operands: A = W2^T (static
// fragments), B = h1. C[m=hidden-col][n=chain] -> each lane's 16 acc
// values belong to its OWN chain; L3 = per-lane dot + xor16 ds_swizzle
// + permlane32_swap pair-sum. L1 forced to v_pk_fma_f16.
// 256 blocks x 1 wave; issue/latency-bound on 1 SIMD per CU.

constexpr int Bn = 4096;
constexpr int Tn = 2048;

typedef _Float16 h2v   __attribute__((ext_vector_type(2)));
typedef _Float16 f16x4 __attribute__((ext_vector_type(4)));
typedef _Float16 f16x8 __attribute__((ext_vector_type(8)));
typedef float    f32x4 __attribute__((ext_vector_type(4)));

__global__ __launch_bounds__(64, 1)
void garch_scan_kernel(const float* __restrict__ g_ret,
                       const float* __restrict__ g_lrv,
                       const float* __restrict__ p_omega,
                       const float* __restrict__ p_beta,
                       const float* __restrict__ p_tau1,
                       const float* __restrict__ p_tau2,
                       const float* __restrict__ p_gamma,
                       const float* __restrict__ p_xi,
                       const float* __restrict__ p_phi,
                       const float* __restrict__ p_delta1,
                       const float* __restrict__ p_delta2,
                       const float* __restrict__ p_mu,
                       const float* __restrict__ W1,
                       const float* __restrict__ b1,
                       const float* __restrict__ W2,
                       const float* __restrict__ b2,
                       const float* __restrict__ W3,
                       const float* __restrict__ b3,
                       float* __restrict__ out)
{
    const int l = threadIdx.x;      // 0..63
    const int c = l & 15;           // this lane's chain (B-col / C-col)
    const int g = l >> 4;           // k-slice / m-row group
    const long cb = (long)blockIdx.x * 16;

    const float omega = p_omega[0], beta = p_beta[0];
    const float tau1 = p_tau1[0], tau2 = p_tau2[0], gam = p_gamma[0];
    const float xi = p_xi[0], phi = p_phi[0];
    const float d1 = p_delta1[0], d2 = p_delta2[0], mu = p_mu[0];
    const float b3s = b3[0];

    // W1/b1 packed f16 pairs; pair q = 4*kt + jp covers k = 32*kt + 8*g + 2*jp
    h2v w1xp[8], w1yp[8], w1zp[8], b1p[8];
#pragma unroll
    for (int q = 0; q < 8; ++q) {
        const int kt = q >> 2, jp = q & 3;
        const int k0 = 32 * kt + 8 * g + 2 * jp;
        h2v a;
        a.x = (_Float16)W1[k0];        a.y = (_Float16)W1[k0 + 1];        w1xp[q] = a;
        a.x = (_Float16)W1[64 + k0];   a.y = (_Float16)W1[64 + k0 + 1];   w1yp[q] = a;
        a.x = (_Float16)W1[128 + k0];  a.y = (_Float16)W1[128 + k0 + 1];  w1zp[q] = a;
        a.x = (_Float16)b1[k0];        a.y = (_Float16)b1[k0 + 1];        b1p[q] = a;
    }

    // W2^T A-fragments: A[m=16*mt + (l&15)][k=32*kt+8*g+j] = W2[k][m]
    f16x8 aw2[2][4];
#pragma unroll
    for (int kt = 0; kt < 2; ++kt)
#pragma unroll
        for (int mt = 0; mt < 4; ++mt)
#pragma unroll
            for (int j = 0; j < 8; ++j)
                aw2[kt][mt][j] = (_Float16)W2[(32 * kt + 8 * g + j) * 64 + 16 * mt + c];

    // C-init = b2[m], m = 16*mt + 4*g + i  (C row = 4*(l>>4)+i, col = chain)
    f32x4 binit[4];
#pragma unroll
    for (int mt = 0; mt < 4; ++mt)
#pragma unroll
        for (int i = 0; i < 4; ++i)
            binit[mt][i] = b2[16 * mt + 4 * g + i];

    // W3 packed pairs matching acc pair order
    h2v w3pk[4][2];
#pragma unroll
    for (int mt = 0; mt < 4; ++mt) {
        h2v a;
        a.x = (_Float16)W3[16 * mt + 4 * g + 0];
        a.y = (_Float16)W3[16 * mt + 4 * g + 1];
        w3pk[mt][0] = a;
        a.x = (_Float16)W3[16 * mt + 4 * g + 2];
        a.y = (_Float16)W3[16 * mt + 4 * g + 3];
        w3pk[mt][1] = a;
    }

    __shared__ __align__(16) float2 lds_in[16][66];   // (r, lrv)
    __shared__ __align__(16) float2 ldsA[16][66];     // (enh, lx)
    __shared__ __align__(16) float2 ldsB[16][66];     // (z, u)

    const float* rbase = g_ret + cb * Tn;
    const float* lbase = g_lrv + cb * Tn;
    const float2* pin = &lds_in[c][0];
    float2* pA = &ldsA[c][0];
    float2* pB = &ldsB[c][0];

    float lh = 0.0f, zp = 0.0f, z2m1 = -1.0f, up = 0.0f;  // chain state
    const h2v hzero = {(_Float16)0.0f, (_Float16)0.0f};

    for (int t0 = 0; t0 < Tn; t0 += 64) {
        // ---- stage 64 steps of (r, lrv) for all 16 chains ----
        {
            float tr[16], tl[16];
#pragma unroll
            for (int k = 0; k < 16; ++k) {
                tr[k] = rbase[(long)k * Tn + t0 + l];
                tl[k] = lbase[(long)k * Tn + t0 + l];
            }
#pragma unroll
            for (int k = 0; k < 16; ++k)
                lds_in[k][l] = make_float2(tr[k], tl[k]);
        }
        asm volatile("" ::: "memory");   // DS in-order within wave

#pragma unroll 4
        for (int tw = 0; tw < 64; ++tw) {
            const float2 rl = pin[tw];
            const float r_t = rl.x, lrv_t = rl.y;

            // recurrence (3-deep tree)
            const float sA = fmaf(beta, lh, omega);
            const float sB = fmaf(tau2, z2m1, tau1 * zp);
            const float sC = fmaf(gam, up, sA + sB);
            const float lh_t = (t0 + tw == 0) ? lrv_t : sC;  // lh0 = lrv0

            const float z_t  = (r_t - mu) * __expf(-0.5f * lh_t);
            const float z2n  = fmaf(z_t, z_t, -1.0f);
            const float dlt  = fmaf(d2, z2n, d1 * z_t);
            const float a_t  = fmaf(phi, lh_t, xi) + dlt;
            const float u_t  = lrv_t - a_t;
            const float lx_t = a_t + u_t;

            // ---- L1 packed f16 (forced v_pk_fma_f16) ----
            const h2v lh2 = __builtin_bit_cast(h2v, __builtin_amdgcn_cvt_pkrtz(lh_t, lh_t));
            const h2v zz2 = __builtin_bit_cast(h2v, __builtin_amdgcn_cvt_pkrtz(z_t,  z_t));
            const h2v uu2 = __builtin_bit_cast(h2v, __builtin_amdgcn_cvt_pkrtz(u_t,  u_t));

            h2v q[8];
#pragma unroll
            for (int p = 0; p < 8; ++p) {
                h2v h = __builtin_elementwise_fma(w1xp[p], lh2, b1p[p]);
                h = __builtin_elementwise_fma(w1yp[p], zz2, h);
                h = __builtin_elementwise_fma(w1zp[p], uu2, h);
                q[p] = __builtin_elementwise_max(h, hzero);
            }
            const f16x4 lo0 = __builtin_shufflevector(q[0], q[1], 0, 1, 2, 3);
            const f16x4 hi0 = __builtin_shufflevector(q[2], q[3], 0, 1, 2, 3);
            const f16x8 bf0 = __builtin_shufflevector(lo0, hi0, 0, 1, 2, 3, 4, 5, 6, 7);
            const f16x4 lo1 = __builtin_shufflevector(q[4], q[5], 0, 1, 2, 3);
            const f16x4 hi1 = __builtin_shufflevector(q[6], q[7], 0, 1, 2, 3);
            const f16x8 bf1 = __builtin_shufflevector(lo1, hi1, 0, 1, 2, 3, 4, 5, 6, 7);

            // ---- L2: D[m][chain] = W2^T h1^T + b2 : A = W2^T, B = h1 ----
            f32x4 acc[4];
#pragma unroll
            for (int mt = 0; mt < 4; ++mt) {
                f32x4 t4 = __builtin_amdgcn_mfma_f32_16x16x32_f16(aw2[0][mt], bf0, binit[mt], 0, 0, 0);
                acc[mt]  = __builtin_amdgcn_mfma_f32_16x16x32_f16(aw2[1][mt], bf1, t4, 0, 0, 0);
            }

            // ---- L3: per-lane dot over this lane's 16 hidden-cols ----
            float dA = 0.0f, dB = 0.0f;
#pragma unroll
            for (int mt = 0; mt < 4; ++mt) {
                h2v p01 = __builtin_bit_cast(h2v, __builtin_amdgcn_cvt_pkrtz(acc[mt][0], acc[mt][1]));
                h2v p23 = __builtin_bit_cast(h2v, __builtin_amdgcn_cvt_pkrtz(acc[mt][2], acc[mt][3]));
                p01 = __builtin_elementwise_max(p01, hzero);
                p23 = __builtin_elementwise_max(p23, hzero);
                if (mt < 2) {
                    dA = __builtin_amdgcn_fdot2(p01, w3pk[mt][0], dA, false);
                    dA = __builtin_amdgcn_fdot2(p23, w3pk[mt][1], dA, false);
                } else {
                    dB = __builtin_amdgcn_fdot2(p01, w3pk[mt][0], dB, false);
                    dB = __builtin_amdgcn_fdot2(p23, w3pk[mt][1], dB, false);
                }
            }
            const float part = dA + dB;

            // ---- sum the 4 lane-groups: xor16 (ds_swizzle) + xor32 (permlane) ----
            const float s16 = part + __builtin_bit_cast(float,
                __builtin_amdgcn_ds_swizzle(__builtin_bit_cast(int, part), 0x401F));
            float nns;
#if __has_builtin(__builtin_amdgcn_permlane32_swap)
            {
                // pair-sum trick: r2[0] + r2[1] == x[l] + x[l^32] on every lane
                auto r2 = __builtin_amdgcn_permlane32_swap(
                    __builtin_bit_cast(unsigned int, s16),
                    __builtin_bit_cast(unsigned int, s16), false, false);
                nns = __builtin_bit_cast(float, (unsigned int)r2[0])
                    + __builtin_bit_cast(float, (unsigned int)r2[1]);
            }
#else
            nns = s16 + __shfl_xor(s16, 32, 64);
#endif
            const float nn  = nns + b3s;
            const float enh = fmaf(0.01f, nn, lh_t);
            if (l < 16) {
                pA[tw] = make_float2(enh, lx_t);
                pB[tw] = make_float2(z_t, u_t);
            }
            lh = enh; zp = z_t; z2m1 = z2n; up = u_t;
        }

        asm volatile("" ::: "memory");
        // ---- drain: lane -> chain cd=l>>2, 16-step block tb=l&3 ----
        const int  cd = l >> 2, tb = l & 3;
        const long chd = cb + cd;
        float* oLH = out + 0l * Bn * Tn + chd * Tn + t0 + 16 * tb;
        float* oLX = out + 1l * Bn * Tn + chd * Tn + t0 + 16 * tb;
        float* oZ  = out + 2l * Bn * Tn + chd * Tn + t0 + 16 * tb;
        float* oU  = out + 3l * Bn * Tn + chd * Tn + t0 + 16 * tb;
#pragma unroll
        for (int i = 0; i < 4; ++i) {
            const float4 pA01 = *(const float4*)&ldsA[cd][16 * tb + 4 * i];
            const float4 pA23 = *(const float4*)&ldsA[cd][16 * tb + 4 * i + 2];
            const float4 pB01 = *(const float4*)&ldsB[cd][16 * tb + 4 * i];
            const float4 pB23 = *(const float4*)&ldsB[cd][16 * tb + 4 * i + 2];
            *(float4*)&oLH[4 * i] = make_float4(pA01.x, pA01.z, pA23.x, pA23.z);
            *(float4*)&oLX[4 * i] = make_float4(pA01.y, pA01.w, pA23.y, pA23.w);
            *(float4*)&oZ [4 * i] = make_float4(pB01.x, pB01.z, pB23.x, pB23.z);
            *(float4*)&oU [4 * i] = make_float4(pB01.y, pB01.w, pB23.y, pB23.w);
        }
    }
}

extern "C" void kernel_launch(void* const* d_in, const int* in_sizes, int n_in,
                              void* d_out, int out_size, void* d_ws, size_t ws_size,
                              hipStream_t stream) {
    const float* g_ret = (const float*)d_in[0];
    const float* g_lrv = (const float*)d_in[1];
    const float* p_omega  = (const float*)d_in[2];
    const float* p_beta   = (const float*)d_in[3];
    const float* p_tau1   = (const float*)d_in[4];
    const float* p_tau2   = (const float*)d_in[5];
    const float* p_gamma  = (const float*)d_in[6];
    const float* p_xi     = (const float*)d_in[7];
    const float* p_phi    = (const float*)d_in[8];
    const float* p_delta1 = (const float*)d_in[9];
    const float* p_delta2 = (const float*)d_in[10];
    const float* p_mu     = (const float*)d_in[11];
    const float* W1 = (const float*)d_in[12];
    const float* b1 = (const float*)d_in[13];
    const float* W2 = (const float*)d_in[14];
    const float* b2 = (const float*)d_in[15];
    const float* W3 = (const float*)d_in[16];
    const float* b3 = (const float*)d_in[17];
    float* out = (float*)d_out;

    dim3 grid(Bn / 16), block(64);
    hipLaunchKernelGGL(garch_scan_kernel, grid, block, 0, stream,
                       g_ret, g_lrv, p_omega, p_beta, p_tau1, p_tau2, p_gamma,
                       p_xi, p_phi, p_delta1, p_delta2, p_mu,
                       W1, b1, W2, b2, W3, b3, out);
}

// Round 11
// 662.479 us; speedup vs baseline: 3.2863x; 1.0078x over previous
//
#include <hip/hip_runtime.h>

// RealizedGARCH-PINN scan. B=4096 chains, T=2048 sequential steps.
// R11: 4-wave cooperative block (uses all 4 SIMDs/CU; R10 left 3 idle).
// Block = 256 threads = 4 waves; 16 chains per block; 256 blocks.
// All waves: scalar recurrence + L1 h1-build (redundant, needed as MFMA-B).
// Wave wv: 2 MFMA for its 16 hidden cols (A = W2^T quarter) + 1/4 of L3.
// In-wave reduce: permlane16_swap + permlane32_swap pair-sums.
// Cross-wave: double-buffered part[2][16][4] + ONE __syncthreads per step.

constexpr int Bn = 4096;
constexpr int Tn = 2048;

typedef _Float16 h2v   __attribute__((ext_vector_type(2)));
typedef _Float16 f16x4 __attribute__((ext_vector_type(4)));
typedef _Float16 f16x8 __attribute__((ext_vector_type(8)));
typedef float    f32x4 __attribute__((ext_vector_type(4)));

__device__ __forceinline__ float xor16_sum(float x) {
#if __has_builtin(__builtin_amdgcn_permlane16_swap)
    auto r2 = __builtin_amdgcn_permlane16_swap(
        __builtin_bit_cast(unsigned int, x),
        __builtin_bit_cast(unsigned int, x), false, false);
    return __builtin_bit_cast(float, (unsigned int)r2[0])
         + __builtin_bit_cast(float, (unsigned int)r2[1]);
#else
    return x + __builtin_bit_cast(float,
        __builtin_amdgcn_ds_swizzle(__builtin_bit_cast(int, x), 0x401F));
#endif
}
__device__ __forceinline__ float xor32_sum(float x) {
#if __has_builtin(__builtin_amdgcn_permlane32_swap)
    auto r2 = __builtin_amdgcn_permlane32_swap(
        __builtin_bit_cast(unsigned int, x),
        __builtin_bit_cast(unsigned int, x), false, false);
    return __builtin_bit_cast(float, (unsigned int)r2[0])
         + __builtin_bit_cast(float, (unsigned int)r2[1]);
#else
    return x + __shfl_xor(x, 32, 64);
#endif
}

__global__ __launch_bounds__(256, 1)
void garch_scan_kernel(const float* __restrict__ g_ret,
                       const float* __restrict__ g_lrv,
                       const float* __restrict__ p_omega,
                       const float* __restrict__ p_beta,
                       const float* __restrict__ p_tau1,
                       const float* __restrict__ p_tau2,
                       const float* __restrict__ p_gamma,
                       const float* __restrict__ p_xi,
                       const float* __restrict__ p_phi,
                       const float* __restrict__ p_delta1,
                       const float* __restrict__ p_delta2,
                       const float* __restrict__ p_mu,
                       const float* __restrict__ W1,
                       const float* __restrict__ b1,
                       const float* __restrict__ W2,
                       const float* __restrict__ b2,
                       const float* __restrict__ W3,
                       const float* __restrict__ b3,
                       float* __restrict__ out)
{
    const int tid = threadIdx.x;    // 0..255
    const int wv  = tid >> 6;       // wave id 0..3 (m-quarter owner)
    const int l   = tid & 63;       // lane
    const int c   = l & 15;         // this lane's chain (B-col / C-col)
    const int g   = l >> 4;         // k-slice group
    const long cb = (long)blockIdx.x * 16;

    const float omega = p_omega[0], beta = p_beta[0];
    const float tau1 = p_tau1[0], tau2 = p_tau2[0], gam = p_gamma[0];
    const float xi = p_xi[0], phi = p_phi[0];
    const float d1 = p_delta1[0], d2 = p_delta2[0], mu = p_mu[0];
    const float b3s = b3[0];

    // W1/b1 packed f16 pairs; pair q = 4*kt + jp covers k = 32*kt + 8*g + 2*jp
    h2v w1xp[8], w1yp[8], w1zp[8], b1p[8];
#pragma unroll
    for (int q = 0; q < 8; ++q) {
        const int kt = q >> 2, jp = q & 3;
        const int k0 = 32 * kt + 8 * g + 2 * jp;
        h2v a;
        a.x = (_Float16)W1[k0];        a.y = (_Float16)W1[k0 + 1];        w1xp[q] = a;
        a.x = (_Float16)W1[64 + k0];   a.y = (_Float16)W1[64 + k0 + 1];   w1yp[q] = a;
        a.x = (_Float16)W1[128 + k0];  a.y = (_Float16)W1[128 + k0 + 1];  w1zp[q] = a;
        a.x = (_Float16)b1[k0];        a.y = (_Float16)b1[k0 + 1];        b1p[q] = a;
    }

    // This wave's W2^T A-fragments: A[m=16*wv + c][k=32*kt+8*g+j] = W2[k][m]
    f16x8 aw2k0, aw2k1;
#pragma unroll
    for (int j = 0; j < 8; ++j) {
        aw2k0[j] = (_Float16)W2[(8 * g + j) * 64 + 16 * wv + c];
        aw2k1[j] = (_Float16)W2[(32 + 8 * g + j) * 64 + 16 * wv + c];
    }

    // C-init = b2[m], m = 16*wv + 4*g + i
    f32x4 binit;
#pragma unroll
    for (int i = 0; i < 4; ++i) binit[i] = b2[16 * wv + 4 * g + i];

    // W3 packed pairs for this wave's quarter
    h2v w3a, w3b;
    w3a.x = (_Float16)W3[16 * wv + 4 * g + 0];
    w3a.y = (_Float16)W3[16 * wv + 4 * g + 1];
    w3b.x = (_Float16)W3[16 * wv + 4 * g + 2];
    w3b.y = (_Float16)W3[16 * wv + 4 * g + 3];

    __shared__ __align__(16) float2 lds_in[16][66];   // (r, lrv) per chain/step
    __shared__ __align__(16) float2 ldsA[16][66];     // (enh, lx)
    __shared__ __align__(16) float2 ldsB[16][66];     // (z, u)
    __shared__ __align__(16) float  part[2][16][4];   // per-wave nn partials

    const float* rbase = g_ret + cb * Tn;
    const float* lbase = g_lrv + cb * Tn;
    const float2* pin = &lds_in[c][0];
    float2* pA = &ldsA[c][0];
    float2* pB = &ldsB[c][0];

    float lh = 0.0f, zp = 0.0f, z2m1 = -1.0f, up = 0.0f;  // chain state
    const h2v hzero = {(_Float16)0.0f, (_Float16)0.0f};

    for (int t0 = 0; t0 < Tn; t0 += 64) {
        // ---- stage: wave wv loads chains 4*wv..4*wv+3, 64 steps each ----
#pragma unroll
        for (int k2 = 0; k2 < 4; ++k2) {
            const int ch = 4 * wv + k2;
            const float tr = rbase[(long)ch * Tn + t0 + l];
            const float tl = lbase[(long)ch * Tn + t0 + l];
            lds_in[ch][l] = make_float2(tr, tl);
        }
        __syncthreads();

        for (int tw = 0; tw < 64; ++tw) {
            const float2 rl = pin[tw];
            const float r_t = rl.x, lrv_t = rl.y;

            // recurrence (3-deep tree)
            const float sA = fmaf(beta, lh, omega);
            const float sB = fmaf(tau2, z2m1, tau1 * zp);
            const float sC = fmaf(gam, up, sA + sB);
            const float lh_t = (t0 + tw == 0) ? lrv_t : sC;  // lh0 = lrv0

            const float z_t  = (r_t - mu) * __expf(-0.5f * lh_t);
            const float z2n  = fmaf(z_t, z_t, -1.0f);
            const float dlt  = fmaf(d2, z2n, d1 * z_t);
            const float a_t  = fmaf(phi, lh_t, xi) + dlt;
            const float u_t  = lrv_t - a_t;
            const float lx_t = a_t + u_t;

            // ---- L1 packed f16 (v_pk_fma_f16) ----
            const h2v lh2 = __builtin_bit_cast(h2v, __builtin_amdgcn_cvt_pkrtz(lh_t, lh_t));
            const h2v zz2 = __builtin_bit_cast(h2v, __builtin_amdgcn_cvt_pkrtz(z_t,  z_t));
            const h2v uu2 = __builtin_bit_cast(h2v, __builtin_amdgcn_cvt_pkrtz(u_t,  u_t));

            h2v q[8];
#pragma unroll
            for (int p = 0; p < 8; ++p) {
                h2v h = __builtin_elementwise_fma(w1xp[p], lh2, b1p[p]);
                h = __builtin_elementwise_fma(w1yp[p], zz2, h);
                h = __builtin_elementwise_fma(w1zp[p], uu2, h);
                q[p] = __builtin_elementwise_max(h, hzero);
            }
            const f16x4 lo0 = __builtin_shufflevector(q[0], q[1], 0, 1, 2, 3);
            const f16x4 hi0 = __builtin_shufflevector(q[2], q[3], 0, 1, 2, 3);
            const f16x8 bf0 = __builtin_shufflevector(lo0, hi0, 0, 1, 2, 3, 4, 5, 6, 7);
            const f16x4 lo1 = __builtin_shufflevector(q[4], q[5], 0, 1, 2, 3);
            const f16x4 hi1 = __builtin_shufflevector(q[6], q[7], 0, 1, 2, 3);
            const f16x8 bf1 = __builtin_shufflevector(lo1, hi1, 0, 1, 2, 3, 4, 5, 6, 7);

            // ---- L2 quarter: D[m=16wv..][chain] = W2^T h1 + b2 (2 MFMA) ----
            f32x4 t4  = __builtin_amdgcn_mfma_f32_16x16x32_f16(aw2k0, bf0, binit, 0, 0, 0);
            f32x4 accv = __builtin_amdgcn_mfma_f32_16x16x32_f16(aw2k1, bf1, t4, 0, 0, 0);

            // ---- L3 quarter: per-lane dot over this lane's 4 hidden-cols ----
            h2v p01 = __builtin_bit_cast(h2v, __builtin_amdgcn_cvt_pkrtz(accv[0], accv[1]));
            h2v p23 = __builtin_bit_cast(h2v, __builtin_amdgcn_cvt_pkrtz(accv[2], accv[3]));
            p01 = __builtin_elementwise_max(p01, hzero);
            p23 = __builtin_elementwise_max(p23, hzero);
            const float d0 = __builtin_amdgcn_fdot2(p01, w3a,
                               __builtin_amdgcn_fdot2(p23, w3b, 0.0f, false), false);

            // ---- in-wave reduce over g-groups (keep chain c) ----
            const float Sw = xor32_sum(xor16_sum(d0));   // wave's partial, all lanes

            // ---- cross-wave combine: double-buffered LDS + one barrier ----
            part[tw & 1][c][wv] = Sw;       // 4 dup lanes same addr: benign
            __syncthreads();
            const float4 ps = *(const float4*)&part[tw & 1][c][0];
            const float nn  = ((ps.x + ps.y) + (ps.z + ps.w)) + b3s;
            const float enh = fmaf(0.01f, nn, lh_t);

            if (wv == 0) {                  // wave-uniform branch (SALU)
                pA[tw] = make_float2(enh, lx_t);
                pB[tw] = make_float2(z_t, u_t);
            }
            lh = enh; zp = z_t; z2m1 = z2n; up = u_t;
        }

        __syncthreads();
        // ---- drain with all 256 threads: chain cd, 4 steps at 4*tb ----
        const int cd = tid >> 4, tb = tid & 15;
        const long chd = cb + cd;
        float* oLH = out + 0l * Bn * Tn + chd * Tn + t0 + 4 * tb;
        float* oLX = out + 1l * Bn * Tn + chd * Tn + t0 + 4 * tb;
        float* oZ  = out + 2l * Bn * Tn + chd * Tn + t0 + 4 * tb;
        float* oU  = out + 3l * Bn * Tn + chd * Tn + t0 + 4 * tb;
        const float4 qA01 = *(const float4*)&ldsA[cd][4 * tb];      // steps 4tb,4tb+1
        const float4 qA23 = *(const float4*)&ldsA[cd][4 * tb + 2];  // steps 4tb+2,+3
        const float4 qB01 = *(const float4*)&ldsB[cd][4 * tb];
        const float4 qB23 = *(const float4*)&ldsB[cd][4 * tb + 2];
        *(float4*)oLH = make_float4(qA01.x, qA01.z, qA23.x, qA23.z);
        *(float4*)oLX = make_float4(qA01.y, qA01.w, qA23.y, qA23.w);
        *(float4*)oZ  = make_float4(qB01.x, qB01.z, qB23.x, qB23.z);
        *(float4*)oU  = make_float4(qB01.y, qB01.w, qB23.y, qB23.w);
        __syncthreads();
    }
}

extern "C" void kernel_launch(void* const* d_in, const int* in_sizes, int n_in,
                              void* d_out, int out_size, void* d_ws, size_t ws_size,
                              hipStream_t stream) {
    const float* g_ret = (const float*)d_in[0];
    const float* g_lrv = (const float*)d_in[1];
    const float* p_omega  = (const float*)d_in[2];
    const float* p_beta   = (const float*)d_in[3];
    const float* p_tau1   = (const float*)d_in[4];
    const float* p_tau2   = (const float*)d_in[5];
    const float* p_gamma  = (const float*)d_in[6];
    const float* p_xi     = (const float*)d_in[7];
    const float* p_phi    = (const float*)d_in[8];
    const float* p_delta1 = (const float*)d_in[9];
    const float* p_delta2 = (const float*)d_in[10];
    const float* p_mu     = (const float*)d_in[11];
    const float* W1 = (const float*)d_in[12];
    const float* b1 = (const float*)d_in[13];
    const float* W2 = (const float*)d_in[14];
    const float* b2 = (const float*)d_in[15];
    const float* W3 = (const float*)d_in[16];
    const float* b3 = (const float*)d_in[17];
    float* out = (float*)d_out;

    dim3 grid(Bn / 16), block(256);
    hipLaunchKernelGGL(garch_scan_kernel, grid, block, 0, stream,
                       g_ret, g_lrv, p_omega, p_beta, p_tau1, p_tau2, p_gamma,
                       p_xi, p_phi, p_delta1, p_delta2, p_mu,
                       W1, b1, W2, b2, W3, b3, out);
}